// Round 7
// baseline (752.047 us; speedup 1.0000x reference)
//
#include <hip/hip_runtime.h>
#include <math.h>

#define NN 50000
#define EE 800000

// ---------------- CSR build ----------------

__global__ __launch_bounds__(256) void k_hist(const int* __restrict__ dst, int* __restrict__ deg) {
    int e = blockIdx.x * 256 + threadIdx.x;
    if (e < EE) atomicAdd(&deg[dst[e]], 1);
}

// single-block exclusive scan of deg[0..NN) -> rowptr; deg becomes pos (= rowptr copy)
__global__ __launch_bounds__(1024) void k_scan(int* __restrict__ deg, int* __restrict__ rowptr) {
    __shared__ int part[1024];
    const int t  = threadIdx.x;
    const int CH = (NN + 1023) / 1024;
    const int b  = t * CH;
    const int e  = min(b + CH, NN);
    int sum = 0;
    for (int i = b; i < e; i++) sum += deg[i];
    part[t] = sum;
    __syncthreads();
    for (int off = 1; off < 1024; off <<= 1) {
        int v = (t >= off) ? part[t - off] : 0;
        __syncthreads();
        part[t] += v;
        __syncthreads();
    }
    int run = (t == 0) ? 0 : part[t - 1];
    for (int i = b; i < e; i++) {
        int d = deg[i];
        rowptr[i] = run;
        deg[i]    = run;   // pos
        run += d;
    }
    if (t == 0) rowptr[NN] = EE;
}

// eidx[p] = edge id at CSR slot p; esrc[p] = src of that edge.
__global__ __launch_bounds__(256) void k_scatter(const int* __restrict__ src, const int* __restrict__ dst,
                                                 int* __restrict__ pos, int* __restrict__ eidx,
                                                 int* __restrict__ esrc) {
    int e = blockIdx.x * 256 + threadIdx.x;
    if (e < EE) {
        int d = dst[e];
        int p = atomicAdd(&pos[d], 1);
        eidx[p] = e;
        esrc[p] = src[e];
    }
}

// ---------------- per-layer kernels ----------------

// K1: per-node fused transform, weights staged in LDS, 4 nodes per wave
// iteration so each weight ds_read feeds 4 fmas (r4-proven body).
__global__ __launch_bounds__(256) void node_transform(
    const float* __restrict__ hin, const float* __restrict__ pot,
    const float* __restrict__ Wpot, const float* __restrict__ bpot,
    const float* __restrict__ fcW, const float* __restrict__ fcU,
    const float* __restrict__ a, const float* __restrict__ gate,
    float* __restrict__ z, float* __restrict__ zs, float* __restrict__ zd,
    float* __restrict__ base)
{
    __shared__ float sW[64 * 64];
    __shared__ float sU[64 * 64];
    __shared__ float sP[16 * 64];
    __shared__ float sb[64], sg[64], sas[64], sad[64];
    for (int i = threadIdx.x; i < 64 * 64; i += 256) { sW[i] = fcW[i]; sU[i] = fcU[i]; }
    for (int i = threadIdx.x; i < 16 * 64; i += 256) sP[i] = Wpot[i];
    if (threadIdx.x < 64) {
        sb[threadIdx.x]  = bpot[threadIdx.x];
        sg[threadIdx.x]  = gate[threadIdx.x];
        sas[threadIdx.x] = a[threadIdx.x];
        sad[threadIdx.x] = a[64 + threadIdx.x];
    }
    __syncthreads();

    const int lane   = threadIdx.x & 63;
    const int wave   = blockIdx.x * 4 + (threadIdx.x >> 6);
    const int nwaves = gridDim.x * 4;

    // NN % 4 == 0, so every group of 4 is full.
    for (int n0 = wave * 4; n0 < NN; n0 += nwaves * 4) {
        float h[4], p[4];
#pragma unroll
        for (int c = 0; c < 4; c++) {
            h[c] = hin[(size_t)(n0 + c) * 64 + lane];
            p[c] = (lane < 16) ? pot[(size_t)(n0 + c) * 16 + lane] : 0.f;
        }
        float az[4] = {0.f, 0.f, 0.f, 0.f};
        float au[4] = {0.f, 0.f, 0.f, 0.f};
#pragma unroll
        for (int k = 0; k < 64; k++) {
            const float w = sW[k * 64 + lane];
            const float u = sU[k * 64 + lane];
#pragma unroll
            for (int c = 0; c < 4; c++) {
                const float hk = __shfl(h[c], k);
                az[c] = fmaf(hk, w, az[c]);
                au[c] = fmaf(hk, u, au[c]);
            }
        }
        float vv[4];
#pragma unroll
        for (int c = 0; c < 4; c++) vv[c] = sb[lane];
#pragma unroll
        for (int k = 0; k < 16; k++) {
            const float pw = sP[k * 64 + lane];
#pragma unroll
            for (int c = 0; c < 4; c++) vv[c] = fmaf(__shfl(p[c], k), pw, vv[c]);
        }
#pragma unroll
        for (int c = 0; c < 4; c++) {
            const int n = n0 + c;
            const float zj = az[c];
            float rs = zj * sas[lane];
            float rd = zj * sad[lane];
#pragma unroll
            for (int off = 32; off; off >>= 1) {
                rs += __shfl_xor(rs, off);
                rd += __shfl_xor(rd, off);
            }
            z[(size_t)n * 64 + lane]    = zj;
            base[(size_t)n * 64 + lane] = sg[lane] * tanhf(vv[c]) * au[c];
            if (lane == 0) { zs[n] = rs; zd[n] = rd; }
        }
    }
}

// K2: 4-lanes-per-edge streaming dot for BOTH layers.
// lane q of each 4-lane group handles row float4-chunks {q, q+4, q+8, q+12}:
// every load instruction touches 16 fully-used 64B chunks (no overfetch),
// 16 in-lane fmas per array, and only a 2-step shuffle reduce.
__global__ __launch_bounds__(256) void edge_dot2(
    const float* __restrict__ et0, const float* __restrict__ et1,
    const float* __restrict__ a0, const float* __restrict__ a1,
    float* __restrict__ sc0, float* __restrict__ sc1)
{
    const int lane = threadIdx.x & 63;
    const int q    = lane & 3;
    const int sub  = lane >> 2;                               // 0..15
    const int wid  = (blockIdx.x * 256 + threadIdx.x) >> 6;   // global wave id
    const int nw   = (gridDim.x * 256) >> 6;

    float4 A0q[4], A1q[4];
#pragma unroll
    for (int u = 0; u < 4; u++) {
        A0q[u] = *reinterpret_cast<const float4*>(a0 + 128 + (u * 4 + q) * 4);
        A1q[u] = *reinterpret_cast<const float4*>(a1 + 128 + (u * 4 + q) * 4);
    }
    const float4* __restrict__ e0 = reinterpret_cast<const float4*>(et0);
    const float4* __restrict__ e1 = reinterpret_cast<const float4*>(et1);

    for (int g = wid; g < EE / 16; g += nw) {
        const int e = g * 16 + sub;
        const size_t rb = (size_t)e * 16;
        float4 v0[4], v1[4];
#pragma unroll
        for (int u = 0; u < 4; u++) v0[u] = e0[rb + u * 4 + q];
#pragma unroll
        for (int u = 0; u < 4; u++) v1[u] = e1[rb + u * 4 + q];
        float r0 = 0.f, r1 = 0.f;
#pragma unroll
        for (int u = 0; u < 4; u++) {
            r0 = fmaf(v0[u].x, A0q[u].x, fmaf(v0[u].y, A0q[u].y, fmaf(v0[u].z, A0q[u].z, fmaf(v0[u].w, A0q[u].w, r0))));
            r1 = fmaf(v1[u].x, A1q[u].x, fmaf(v1[u].y, A1q[u].y, fmaf(v1[u].z, A1q[u].z, fmaf(v1[u].w, A1q[u].w, r1))));
        }
        r0 += __shfl_xor(r0, 1); r0 += __shfl_xor(r0, 2);
        r1 += __shfl_xor(r1, 1); r1 += __shfl_xor(r1, 2);
        if (q == 0) { sc0[e] = r0; sc1[e] = r1; }
    }
}

// K3: fused per-node softmax + aggregate + finalize. Wave per node.
// score gather via eidx (sc is L2/L3-resident, 3.2 MB).
__global__ __launch_bounds__(256) void node_sm_agg(
    const int* __restrict__ rowptr, const int* __restrict__ eidx, const int* __restrict__ esrc,
    const float* __restrict__ score_t, const float* __restrict__ zs, const float* __restrict__ zd,
    const float* __restrict__ z, const float* __restrict__ base,
    float* __restrict__ out)
{
    const int lane = threadIdx.x & 63;
    const int n    = blockIdx.x * 4 + (threadIdx.x >> 6);
    if (n >= NN) return;

    const int s0  = rowptr[n], s1 = rowptr[n + 1];
    const int deg = s1 - s0;
    const float zdn = zd[n];

    float acc = 0.f;
    float ds;

    if (deg <= 64) {
        const int j = s0 + lane;
        int   sv = 0;
        float sc = -INFINITY;
        if (j < s1) {
            sv = esrc[j];
            float v = score_t[eidx[j]] + zs[sv] + zdn;
            sc = (v >= 0.f) ? v : 0.01f * v;
        }
        float mx = sc;
#pragma unroll
        for (int off = 32; off; off >>= 1) mx = fmaxf(mx, __shfl_xor(mx, off));
        float ex = (j < s1) ? __expf(sc - mx) : 0.f;
        ds = ex;
#pragma unroll
        for (int off = 32; off; off >>= 1) ds += __shfl_xor(ds, off);
        for (int t = 0; t < deg; t++) {
            int   s = __shfl(sv, t);
            float e = __shfl(ex, t);
            acc = fmaf(e, z[(size_t)s * 64 + lane], acc);
        }
    } else {
        // generic fallback (deg > 64): two passes, recompute scores.
        float mx = -INFINITY;
        for (int j = s0 + lane; j < s1; j += 64) {
            float v = score_t[eidx[j]] + zs[esrc[j]] + zdn;
            v = (v >= 0.f) ? v : 0.01f * v;
            mx = fmaxf(mx, v);
        }
#pragma unroll
        for (int off = 32; off; off >>= 1) mx = fmaxf(mx, __shfl_xor(mx, off));
        ds = 0.f;
        for (int c0 = s0; c0 < s1; c0 += 64) {
            const int j = c0 + lane;
            int   sv = 0;
            float ex = 0.f;
            if (j < s1) {
                sv = esrc[j];
                float v = score_t[eidx[j]] + zs[sv] + zdn;
                v = (v >= 0.f) ? v : 0.01f * v;
                ex = __expf(v - mx);
            }
            ds += ex;
            const int cnt = min(64, s1 - c0);
            for (int t = 0; t < cnt; t++) {
                int   s = __shfl(sv, t);
                float e = __shfl(ex, t);
                acc = fmaf(e, z[(size_t)s * 64 + lane], acc);
            }
        }
#pragma unroll
        for (int off = 32; off; off >>= 1) ds += __shfl_xor(ds, off);
    }

    float r = 1.f / ((ds == 0.f) ? 1.f : ds);
    const size_t o = (size_t)n * 64 + lane;
    out[o] = acc * r + base[o];
}

// ---------------- launch ----------------

extern "C" void kernel_launch(void* const* d_in, const int* in_sizes, int n_in,
                              void* d_out, int out_size, void* d_ws, size_t ws_size,
                              hipStream_t stream)
{
    const float* attr  = (const float*)d_in[0];
    const float* pot0  = (const float*)d_in[1];
    const float* pot1  = (const float*)d_in[2];
    const float* et0   = (const float*)d_in[3];
    const float* et1   = (const float*)d_in[4];
    const float* Wpot  = (const float*)d_in[5];
    const float* bpot  = (const float*)d_in[6];
    const float* fcW0  = (const float*)d_in[7];
    const float* fcU0  = (const float*)d_in[8];
    const float* a0    = (const float*)d_in[9];
    const float* gate0 = (const float*)d_in[10];
    const float* fcW1  = (const float*)d_in[11];
    const float* fcU1  = (const float*)d_in[12];
    const float* a1    = (const float*)d_in[13];
    const float* gate1 = (const float*)d_in[14];
    const int*   src   = (const int*)d_in[15];
    const int*   dst   = (const int*)d_in[16];

    float* out = (float*)d_out;

    // workspace layout
    float* ws      = (float*)d_ws;
    float* z       = ws;                    // NN*64
    float* base    = z + NN * 64;           // NN*64
    float* zs      = base + NN * 64;        // NN
    float* zd      = zs + NN;               // NN
    float* sc0     = zd + NN;               // EE (edge order)
    float* sc1     = sc0 + EE;              // EE (edge order)
    int*   rowptr  = (int*)(sc1 + EE);      // NN+1
    int*   deg     = rowptr + NN + 1;       // NN (becomes pos)
    int*   eidx    = deg + NN;              // EE
    int*   esrc    = eidx + EE;             // EE

    const int eblk = (EE + 255) / 256;
    const int nblk = (NN + 3) / 4;

    // CSR build (shared by both layers)
    hipMemsetAsync(deg, 0, NN * sizeof(int), stream);
    k_hist<<<eblk, 256, 0, stream>>>(dst, deg);
    k_scan<<<1, 1024, 0, stream>>>(deg, rowptr);
    k_scatter<<<eblk, 256, 0, stream>>>(src, dst, deg, eidx, esrc);

    // streaming edge dots for both layers (edge-order scores)
    edge_dot2<<<2048, 256, 0, stream>>>(et0, et1, a0, a1, sc0, sc1);

    // ---------------- layer 0 ----------------
    node_transform<<<1024, 256, 0, stream>>>(attr, pot0, Wpot, bpot, fcW0, fcU0,
                                             a0, gate0, z, zs, zd, base);
    node_sm_agg<<<nblk, 256, 0, stream>>>(rowptr, eidx, esrc, sc0, zs, zd, z, base, out);

    // ---------------- layer 1 ---------------- (h = out from layer 0)
    node_transform<<<1024, 256, 0, stream>>>(out, pot1, Wpot, bpot, fcW1, fcU1,
                                             a1, gate1, z, zs, zd, base);
    node_sm_agg<<<nblk, 256, 0, stream>>>(rowptr, eidx, esrc, sc1, zs, zd, z, base, out);
}

// Round 8
// 477.115 us; speedup vs baseline: 1.5762x; 1.5762x over previous
//
#include <hip/hip_runtime.h>
#include <math.h>

#define NN 50000
#define EE 800000
#define BM 64

// ---------------- CSR build ----------------

__global__ __launch_bounds__(256) void k_hist(const int* __restrict__ dst, int* __restrict__ deg) {
    int e = blockIdx.x * 256 + threadIdx.x;
    if (e < EE) atomicAdd(&deg[dst[e]], 1);
}

// single-block exclusive scan of deg[0..NN) -> rowptr; deg becomes pos (= rowptr copy)
__global__ __launch_bounds__(1024) void k_scan(int* __restrict__ deg, int* __restrict__ rowptr) {
    __shared__ int part[1024];
    const int t  = threadIdx.x;
    const int CH = (NN + 1023) / 1024;
    const int b  = t * CH;
    const int e  = min(b + CH, NN);
    int sum = 0;
    for (int i = b; i < e; i++) sum += deg[i];
    part[t] = sum;
    __syncthreads();
    for (int off = 1; off < 1024; off <<= 1) {
        int v = (t >= off) ? part[t - off] : 0;
        __syncthreads();
        part[t] += v;
        __syncthreads();
    }
    int run = (t == 0) ? 0 : part[t - 1];
    for (int i = b; i < e; i++) {
        int d = deg[i];
        rowptr[i] = run;
        deg[i]    = run;   // pos
        run += d;
    }
    if (t == 0) rowptr[NN] = EE;
}

// eidx[p] = edge id at CSR slot p; esrc[p] = src of that edge.
__global__ __launch_bounds__(256) void k_scatter(const int* __restrict__ src, const int* __restrict__ dst,
                                                 int* __restrict__ pos, int* __restrict__ eidx,
                                                 int* __restrict__ esrc) {
    int e = blockIdx.x * 256 + threadIdx.x;
    if (e < EE) {
        int d = dst[e];
        int p = atomicAdd(&pos[d], 1);
        eidx[p] = e;
        esrc[p] = src[e];
    }
}

// ---------------- per-layer kernels ----------------

#define FMA4(acc, s, v) do { \
    (acc).x = fmaf((s), (v).x, (acc).x); \
    (acc).y = fmaf((s), (v).y, (acc).y); \
    (acc).z = fmaf((s), (v).z, (acc).z); \
    (acc).w = fmaf((s), (v).w, (acc).w); } while (0)

__device__ __forceinline__ float dot4(float4 u, float4 v) {
    return fmaf(u.x, v.x, fmaf(u.y, v.y, fmaf(u.z, v.z, u.w * v.w)));
}

// K1: per-node fused transform as an LDS-tiled register-blocked GEMM.
// Block: 64 nodes x 128 outputs (z | zi). Thread: 4 rows x (4+4) cols.
// Also computes zs/zd (shfl reduction) and v=tanh(pot@Wpot+b), base.
__global__ __launch_bounds__(256) void node_transform(
    const float* __restrict__ hin, const float* __restrict__ pot,
    const float* __restrict__ Wpot, const float* __restrict__ bpot,
    const float* __restrict__ fcW, const float* __restrict__ fcU,
    const float* __restrict__ a, const float* __restrict__ gate,
    float* __restrict__ z, float* __restrict__ zs, float* __restrict__ zd,
    float* __restrict__ base)
{
    __shared__ float sAt[64][64];    // sAt[k][m] = h[m0+m][k]   (16 KB)
    __shared__ float sB[64][128];    // [k][j]: j<64 -> fcW, j>=64 -> fcU (32 KB)
    __shared__ float sPot[64][16];   // pot tile (4 KB)
    __shared__ float sWp[16][64];    // Wpot (4 KB)

    const int t     = threadIdx.x;
    const int m0    = blockIdx.x * BM;
    const int valid = min(BM, NN - m0);

    // stage weights: 64x64 W and U -> sB rows
#pragma unroll
    for (int j = 0; j < 4; j++) {
        const int idx = t + j * 256;       // 0..1023
        const int kw = idx >> 4, cq = idx & 15;
        *reinterpret_cast<float4*>(&sB[kw][cq * 4]) =
            *reinterpret_cast<const float4*>(fcW + kw * 64 + cq * 4);
        *reinterpret_cast<float4*>(&sB[kw][64 + cq * 4]) =
            *reinterpret_cast<const float4*>(fcU + kw * 64 + cq * 4);
    }
    // stage h tile transposed + pot tile
    {
        const int m = t >> 2, q = t & 3;
#pragma unroll
        for (int i = 0; i < 4; i++) {
            const int kg = i * 4 + q;
            float4 v4 = make_float4(0.f, 0.f, 0.f, 0.f);
            if (m < valid)
                v4 = *reinterpret_cast<const float4*>(hin + (size_t)(m0 + m) * 64 + kg * 4);
            sAt[kg * 4 + 0][m] = v4.x;
            sAt[kg * 4 + 1][m] = v4.y;
            sAt[kg * 4 + 2][m] = v4.z;
            sAt[kg * 4 + 3][m] = v4.w;
        }
        float4 p4 = make_float4(0.f, 0.f, 0.f, 0.f);
        if (m < valid)
            p4 = *reinterpret_cast<const float4*>(pot + (size_t)(m0 + m) * 16 + q * 4);
        *reinterpret_cast<float4*>(&sPot[m][q * 4]) = p4;
    }
    // stage Wpot
    {
        const int kk = t >> 4, cq = t & 15;
        *reinterpret_cast<float4*>(&sWp[kk][cq * 4]) =
            *reinterpret_cast<const float4*>(Wpot + kk * 64 + cq * 4);
    }
    __syncthreads();

    const int c4 = (t & 15) * 4;   // col base (within 64)
    const int r4 = (t >> 4) * 4;   // row base (within 64)

    float4 az[4], au[4];
#pragma unroll
    for (int i = 0; i < 4; i++) {
        az[i] = make_float4(0.f, 0.f, 0.f, 0.f);
        au[i] = make_float4(0.f, 0.f, 0.f, 0.f);
    }

#pragma unroll 4
    for (int k = 0; k < 64; k++) {
        const float4 a4 = *reinterpret_cast<const float4*>(&sAt[k][r4]);
        const float4 bw = *reinterpret_cast<const float4*>(&sB[k][c4]);
        const float4 bu = *reinterpret_cast<const float4*>(&sB[k][64 + c4]);
        FMA4(az[0], a4.x, bw); FMA4(au[0], a4.x, bu);
        FMA4(az[1], a4.y, bw); FMA4(au[1], a4.y, bu);
        FMA4(az[2], a4.z, bw); FMA4(au[2], a4.z, bu);
        FMA4(az[3], a4.w, bw); FMA4(au[3], a4.w, bu);
    }

    // zs/zd: partial dots then 16-lane-group shfl reduction
    {
        const float4 as4 = *reinterpret_cast<const float4*>(a + c4);
        const float4 ad4 = *reinterpret_cast<const float4*>(a + 64 + c4);
        float ps[4], pd[4];
#pragma unroll
        for (int i = 0; i < 4; i++) { ps[i] = dot4(az[i], as4); pd[i] = dot4(az[i], ad4); }
#pragma unroll
        for (int off = 1; off < 16; off <<= 1) {
#pragma unroll
            for (int i = 0; i < 4; i++) {
                ps[i] += __shfl_xor(ps[i], off);
                pd[i] += __shfl_xor(pd[i], off);
            }
        }
        if ((t & 15) == 0) {
#pragma unroll
            for (int i = 0; i < 4; i++) {
                if (r4 + i < valid) {
                    zs[m0 + r4 + i] = ps[i];
                    zd[m0 + r4 + i] = pd[i];
                }
            }
        }
    }

    // v = tanh(pot@Wpot + b); base = gate * v * zi; store z, base
    {
        const float4 bp4 = *reinterpret_cast<const float4*>(bpot + c4);
        const float4 g4  = *reinterpret_cast<const float4*>(gate + c4);
        float4 vv[4] = {bp4, bp4, bp4, bp4};
#pragma unroll
        for (int kk = 0; kk < 16; kk++) {
            const float4 wp = *reinterpret_cast<const float4*>(&sWp[kk][c4]);
#pragma unroll
            for (int i = 0; i < 4; i++) {
                const float pv = sPot[r4 + i][kk];
                FMA4(vv[i], pv, wp);
            }
        }
#pragma unroll
        for (int i = 0; i < 4; i++) {
            if (r4 + i < valid) {
                const size_t o = (size_t)(m0 + r4 + i) * 64 + c4;
                *reinterpret_cast<float4*>(z + o) = az[i];
                float4 b;
                b.x = g4.x * tanhf(vv[i].x) * au[i].x;
                b.y = g4.y * tanhf(vv[i].y) * au[i].y;
                b.z = g4.z * tanhf(vv[i].z) * au[i].z;
                b.w = g4.w * tanhf(vv[i].w) * au[i].w;
                *reinterpret_cast<float4*>(base + o) = b;
            }
        }
    }
}

// K2: 4-lanes-per-edge streaming dot for BOTH layers.
__global__ __launch_bounds__(256) void edge_dot2(
    const float* __restrict__ et0, const float* __restrict__ et1,
    const float* __restrict__ a0, const float* __restrict__ a1,
    float* __restrict__ sc0, float* __restrict__ sc1)
{
    const int lane = threadIdx.x & 63;
    const int q    = lane & 3;
    const int sub  = lane >> 2;                               // 0..15
    const int wid  = (blockIdx.x * 256 + threadIdx.x) >> 6;   // global wave id
    const int nw   = (gridDim.x * 256) >> 6;

    float4 A0q[4], A1q[4];
#pragma unroll
    for (int u = 0; u < 4; u++) {
        A0q[u] = *reinterpret_cast<const float4*>(a0 + 128 + (u * 4 + q) * 4);
        A1q[u] = *reinterpret_cast<const float4*>(a1 + 128 + (u * 4 + q) * 4);
    }
    const float4* __restrict__ e0 = reinterpret_cast<const float4*>(et0);
    const float4* __restrict__ e1 = reinterpret_cast<const float4*>(et1);

    for (int g = wid; g < EE / 16; g += nw) {
        const int e = g * 16 + sub;
        const size_t rb = (size_t)e * 16;
        float4 v0[4], v1[4];
#pragma unroll
        for (int u = 0; u < 4; u++) v0[u] = e0[rb + u * 4 + q];
#pragma unroll
        for (int u = 0; u < 4; u++) v1[u] = e1[rb + u * 4 + q];
        float r0 = 0.f, r1 = 0.f;
#pragma unroll
        for (int u = 0; u < 4; u++) {
            r0 = fmaf(v0[u].x, A0q[u].x, fmaf(v0[u].y, A0q[u].y, fmaf(v0[u].z, A0q[u].z, fmaf(v0[u].w, A0q[u].w, r0))));
            r1 = fmaf(v1[u].x, A1q[u].x, fmaf(v1[u].y, A1q[u].y, fmaf(v1[u].z, A1q[u].z, fmaf(v1[u].w, A1q[u].w, r1))));
        }
        r0 += __shfl_xor(r0, 1); r0 += __shfl_xor(r0, 2);
        r1 += __shfl_xor(r1, 1); r1 += __shfl_xor(r1, 2);
        if (q == 0) { sc0[e] = r0; sc1[e] = r1; }
    }
}

// K3: fused per-node softmax + aggregate + finalize. Wave per node.
__global__ __launch_bounds__(256) void node_sm_agg(
    const int* __restrict__ rowptr, const int* __restrict__ eidx, const int* __restrict__ esrc,
    const float* __restrict__ score_t, const float* __restrict__ zs, const float* __restrict__ zd,
    const float* __restrict__ z, const float* __restrict__ base,
    float* __restrict__ out)
{
    const int lane = threadIdx.x & 63;
    const int n    = blockIdx.x * 4 + (threadIdx.x >> 6);
    if (n >= NN) return;

    const int s0  = rowptr[n], s1 = rowptr[n + 1];
    const int deg = s1 - s0;
    const float zdn = zd[n];

    float acc = 0.f;
    float ds;

    if (deg <= 64) {
        const int j = s0 + lane;
        int   sv = 0;
        float sc = -INFINITY;
        if (j < s1) {
            sv = esrc[j];
            float v = score_t[eidx[j]] + zs[sv] + zdn;
            sc = (v >= 0.f) ? v : 0.01f * v;
        }
        float mx = sc;
#pragma unroll
        for (int off = 32; off; off >>= 1) mx = fmaxf(mx, __shfl_xor(mx, off));
        float ex = (j < s1) ? __expf(sc - mx) : 0.f;
        ds = ex;
#pragma unroll
        for (int off = 32; off; off >>= 1) ds += __shfl_xor(ds, off);
        for (int t = 0; t < deg; t++) {
            int   s = __shfl(sv, t);
            float e = __shfl(ex, t);
            acc = fmaf(e, z[(size_t)s * 64 + lane], acc);
        }
    } else {
        // generic fallback (deg > 64): two passes, recompute scores.
        float mx = -INFINITY;
        for (int j = s0 + lane; j < s1; j += 64) {
            float v = score_t[eidx[j]] + zs[esrc[j]] + zdn;
            v = (v >= 0.f) ? v : 0.01f * v;
            mx = fmaxf(mx, v);
        }
#pragma unroll
        for (int off = 32; off; off >>= 1) mx = fmaxf(mx, __shfl_xor(mx, off));
        ds = 0.f;
        for (int c0 = s0; c0 < s1; c0 += 64) {
            const int j = c0 + lane;
            int   sv = 0;
            float ex = 0.f;
            if (j < s1) {
                sv = esrc[j];
                float v = score_t[eidx[j]] + zs[sv] + zdn;
                v = (v >= 0.f) ? v : 0.01f * v;
                ex = __expf(v - mx);
            }
            ds += ex;
            const int cnt = min(64, s1 - c0);
            for (int t = 0; t < cnt; t++) {
                int   s = __shfl(sv, t);
                float e = __shfl(ex, t);
                acc = fmaf(e, z[(size_t)s * 64 + lane], acc);
            }
        }
#pragma unroll
        for (int off = 32; off; off >>= 1) ds += __shfl_xor(ds, off);
    }

    float r = 1.f / ((ds == 0.f) ? 1.f : ds);
    const size_t o = (size_t)n * 64 + lane;
    out[o] = acc * r + base[o];
}

// ---------------- launch ----------------

extern "C" void kernel_launch(void* const* d_in, const int* in_sizes, int n_in,
                              void* d_out, int out_size, void* d_ws, size_t ws_size,
                              hipStream_t stream)
{
    const float* attr  = (const float*)d_in[0];
    const float* pot0  = (const float*)d_in[1];
    const float* pot1  = (const float*)d_in[2];
    const float* et0   = (const float*)d_in[3];
    const float* et1   = (const float*)d_in[4];
    const float* Wpot  = (const float*)d_in[5];
    const float* bpot  = (const float*)d_in[6];
    const float* fcW0  = (const float*)d_in[7];
    const float* fcU0  = (const float*)d_in[8];
    const float* a0    = (const float*)d_in[9];
    const float* gate0 = (const float*)d_in[10];
    const float* fcW1  = (const float*)d_in[11];
    const float* fcU1  = (const float*)d_in[12];
    const float* a1    = (const float*)d_in[13];
    const float* gate1 = (const float*)d_in[14];
    const int*   src   = (const int*)d_in[15];
    const int*   dst   = (const int*)d_in[16];

    float* out = (float*)d_out;

    // workspace layout
    float* ws      = (float*)d_ws;
    float* z       = ws;                    // NN*64
    float* base    = z + NN * 64;           // NN*64
    float* zs      = base + NN * 64;        // NN
    float* zd      = zs + NN;               // NN
    float* sc0     = zd + NN;               // EE (edge order)
    float* sc1     = sc0 + EE;              // EE (edge order)
    int*   rowptr  = (int*)(sc1 + EE);      // NN+1
    int*   deg     = rowptr + NN + 1;       // NN (becomes pos)
    int*   eidx    = deg + NN;              // EE
    int*   esrc    = eidx + EE;             // EE

    const int eblk = (EE + 255) / 256;
    const int nblk = (NN + 3) / 4;
    const int tblk = (NN + BM - 1) / BM;

    // CSR build (shared by both layers)
    hipMemsetAsync(deg, 0, NN * sizeof(int), stream);
    k_hist<<<eblk, 256, 0, stream>>>(dst, deg);
    k_scan<<<1, 1024, 0, stream>>>(deg, rowptr);
    k_scatter<<<eblk, 256, 0, stream>>>(src, dst, deg, eidx, esrc);

    // streaming edge dots for both layers (edge-order scores)
    edge_dot2<<<2048, 256, 0, stream>>>(et0, et1, a0, a1, sc0, sc1);

    // ---------------- layer 0 ----------------
    node_transform<<<tblk, 256, 0, stream>>>(attr, pot0, Wpot, bpot, fcW0, fcU0,
                                             a0, gate0, z, zs, zd, base);
    node_sm_agg<<<nblk, 256, 0, stream>>>(rowptr, eidx, esrc, sc0, zs, zd, z, base, out);

    // ---------------- layer 1 ---------------- (h = out from layer 0)
    node_transform<<<tblk, 256, 0, stream>>>(out, pot1, Wpot, bpot, fcW1, fcU1,
                                             a1, gate1, z, zs, zd, base);
    node_sm_agg<<<nblk, 256, 0, stream>>>(rowptr, eidx, esrc, sc1, zs, zd, z, base, out);
}

// Round 9
// 418.571 us; speedup vs baseline: 1.7967x; 1.1399x over previous
//
#include <hip/hip_runtime.h>
#include <math.h>

#define NN 50000
#define EE 800000
#define BM 64
#define DB 1250                  // edge_dot2 blocks
#define DS_ (DB * 256)           // stride; (EE*16) % (DS_*8) == 0  (12.8M / 2.56M = 5)

typedef float f4 __attribute__((ext_vector_type(4)));

// ---------------- CSR build ----------------

__global__ __launch_bounds__(256) void k_hist(const int* __restrict__ dst, int* __restrict__ deg) {
    int e = blockIdx.x * 256 + threadIdx.x;
    if (e < EE) atomicAdd(&deg[dst[e]], 1);
}

__global__ __launch_bounds__(1024) void k_scan(int* __restrict__ deg, int* __restrict__ rowptr) {
    __shared__ int part[1024];
    const int t  = threadIdx.x;
    const int CH = (NN + 1023) / 1024;
    const int b  = t * CH;
    const int e  = min(b + CH, NN);
    int sum = 0;
    for (int i = b; i < e; i++) sum += deg[i];
    part[t] = sum;
    __syncthreads();
    for (int off = 1; off < 1024; off <<= 1) {
        int v = (t >= off) ? part[t - off] : 0;
        __syncthreads();
        part[t] += v;
        __syncthreads();
    }
    int run = (t == 0) ? 0 : part[t - 1];
    for (int i = b; i < e; i++) {
        int d = deg[i];
        rowptr[i] = run;
        deg[i]    = run;   // pos
        run += d;
    }
    if (t == 0) rowptr[NN] = EE;
}

// epair[p] = {edge id, src} at CSR slot p (one 8B store instead of two 4B).
__global__ __launch_bounds__(256) void k_scatter(const int* __restrict__ src, const int* __restrict__ dst,
                                                 int* __restrict__ pos, int2* __restrict__ epair) {
    int e = blockIdx.x * 256 + threadIdx.x;
    if (e < EE) {
        int d = dst[e];
        int p = atomicAdd(&pos[d], 1);
        epair[p] = make_int2(e, src[e]);
    }
}

// ---------------- per-layer kernels ----------------

#define FMA4(acc, s, v) do { \
    (acc).x = fmaf((s), (v).x, (acc).x); \
    (acc).y = fmaf((s), (v).y, (acc).y); \
    (acc).z = fmaf((s), (v).z, (acc).z); \
    (acc).w = fmaf((s), (v).w, (acc).w); } while (0)

__device__ __forceinline__ float dot4(float4 u, float4 v) {
    return fmaf(u.x, v.x, fmaf(u.y, v.y, fmaf(u.z, v.z, u.w * v.w)));
}

// K1: per-node fused transform as an LDS-tiled register-blocked GEMM (r8-proven).
__global__ __launch_bounds__(256) void node_transform(
    const float* __restrict__ hin, const float* __restrict__ pot,
    const float* __restrict__ Wpot, const float* __restrict__ bpot,
    const float* __restrict__ fcW, const float* __restrict__ fcU,
    const float* __restrict__ a, const float* __restrict__ gate,
    float* __restrict__ z, float* __restrict__ zs, float* __restrict__ zd,
    float* __restrict__ base)
{
    __shared__ float sAt[64][64];
    __shared__ float sB[64][128];
    __shared__ float sPot[64][16];
    __shared__ float sWp[16][64];

    const int t     = threadIdx.x;
    const int m0    = blockIdx.x * BM;
    const int valid = min(BM, NN - m0);

#pragma unroll
    for (int j = 0; j < 4; j++) {
        const int idx = t + j * 256;
        const int kw = idx >> 4, cq = idx & 15;
        *reinterpret_cast<float4*>(&sB[kw][cq * 4]) =
            *reinterpret_cast<const float4*>(fcW + kw * 64 + cq * 4);
        *reinterpret_cast<float4*>(&sB[kw][64 + cq * 4]) =
            *reinterpret_cast<const float4*>(fcU + kw * 64 + cq * 4);
    }
    {
        const int m = t >> 2, q = t & 3;
#pragma unroll
        for (int i = 0; i < 4; i++) {
            const int kg = i * 4 + q;
            float4 v4 = make_float4(0.f, 0.f, 0.f, 0.f);
            if (m < valid)
                v4 = *reinterpret_cast<const float4*>(hin + (size_t)(m0 + m) * 64 + kg * 4);
            sAt[kg * 4 + 0][m] = v4.x;
            sAt[kg * 4 + 1][m] = v4.y;
            sAt[kg * 4 + 2][m] = v4.z;
            sAt[kg * 4 + 3][m] = v4.w;
        }
        float4 p4 = make_float4(0.f, 0.f, 0.f, 0.f);
        if (m < valid)
            p4 = *reinterpret_cast<const float4*>(pot + (size_t)(m0 + m) * 16 + q * 4);
        *reinterpret_cast<float4*>(&sPot[m][q * 4]) = p4;
    }
    {
        const int kk = t >> 4, cq = t & 15;
        *reinterpret_cast<float4*>(&sWp[kk][cq * 4]) =
            *reinterpret_cast<const float4*>(Wpot + kk * 64 + cq * 4);
    }
    __syncthreads();

    const int c4 = (t & 15) * 4;
    const int r4 = (t >> 4) * 4;

    float4 az[4], au[4];
#pragma unroll
    for (int i = 0; i < 4; i++) {
        az[i] = make_float4(0.f, 0.f, 0.f, 0.f);
        au[i] = make_float4(0.f, 0.f, 0.f, 0.f);
    }

#pragma unroll 4
    for (int k = 0; k < 64; k++) {
        const float4 a4 = *reinterpret_cast<const float4*>(&sAt[k][r4]);
        const float4 bw = *reinterpret_cast<const float4*>(&sB[k][c4]);
        const float4 bu = *reinterpret_cast<const float4*>(&sB[k][64 + c4]);
        FMA4(az[0], a4.x, bw); FMA4(au[0], a4.x, bu);
        FMA4(az[1], a4.y, bw); FMA4(au[1], a4.y, bu);
        FMA4(az[2], a4.z, bw); FMA4(au[2], a4.z, bu);
        FMA4(az[3], a4.w, bw); FMA4(au[3], a4.w, bu);
    }

    {
        const float4 as4 = *reinterpret_cast<const float4*>(a + c4);
        const float4 ad4 = *reinterpret_cast<const float4*>(a + 64 + c4);
        float ps[4], pd[4];
#pragma unroll
        for (int i = 0; i < 4; i++) { ps[i] = dot4(az[i], as4); pd[i] = dot4(az[i], ad4); }
#pragma unroll
        for (int off = 1; off < 16; off <<= 1) {
#pragma unroll
            for (int i = 0; i < 4; i++) {
                ps[i] += __shfl_xor(ps[i], off);
                pd[i] += __shfl_xor(pd[i], off);
            }
        }
        if ((t & 15) == 0) {
#pragma unroll
            for (int i = 0; i < 4; i++) {
                if (r4 + i < valid) {
                    zs[m0 + r4 + i] = ps[i];
                    zd[m0 + r4 + i] = pd[i];
                }
            }
        }
    }

    {
        const float4 bp4 = *reinterpret_cast<const float4*>(bpot + c4);
        const float4 g4  = *reinterpret_cast<const float4*>(gate + c4);
        float4 vv[4] = {bp4, bp4, bp4, bp4};
#pragma unroll
        for (int kk = 0; kk < 16; kk++) {
            const float4 wp = *reinterpret_cast<const float4*>(&sWp[kk][c4]);
#pragma unroll
            for (int i = 0; i < 4; i++) {
                const float pv = sPot[r4 + i][kk];
                FMA4(vv[i], pv, wp);
            }
        }
#pragma unroll
        for (int i = 0; i < 4; i++) {
            if (r4 + i < valid) {
                const size_t o = (size_t)(m0 + r4 + i) * 64 + c4;
                *reinterpret_cast<float4*>(z + o) = az[i];
                float4 b;
                b.x = g4.x * tanhf(vv[i].x) * au[i].x;
                b.y = g4.y * tanhf(vv[i].y) * au[i].y;
                b.z = g4.z * tanhf(vv[i].z) * au[i].z;
                b.w = g4.w * tanhf(vv[i].w) * au[i].w;
                *reinterpret_cast<float4*>(base + o) = b;
            }
        }
    }
}

// K2: streaming dot for BOTH layers. Lane-contiguous float4 loads (each
// instruction = 1KB contiguous = 8 fully-consumed 128B lines), 8-deep
// strided unroll, NON-TEMPORAL loads (zero reuse -> bypass cache alloc).
__global__ __launch_bounds__(256) void edge_dot2(
    const float* __restrict__ et0, const float* __restrict__ et1,
    const float* __restrict__ a0, const float* __restrict__ a1,
    float* __restrict__ sc0, float* __restrict__ sc1)
{
    const int tid  = blockIdx.x * 256 + threadIdx.x;
    const int lane = threadIdx.x & 63;
    const int p    = tid & 15;
    const float4 A0 = *reinterpret_cast<const float4*>(a0 + 128 + p * 4);
    const float4 A1 = *reinterpret_cast<const float4*>(a1 + 128 + p * 4);
    const f4* __restrict__ e0 = reinterpret_cast<const f4*>(et0);
    const f4* __restrict__ e1 = reinterpret_cast<const f4*>(et1);

    for (int i = tid; i < EE * 16; i += DS_ * 8) {
        f4 v0[8], v1[8];
#pragma unroll
        for (int u = 0; u < 8; u++) v0[u] = __builtin_nontemporal_load(e0 + i + u * DS_);
#pragma unroll
        for (int u = 0; u < 8; u++) v1[u] = __builtin_nontemporal_load(e1 + i + u * DS_);
        float r0[8], r1[8];
#pragma unroll
        for (int u = 0; u < 8; u++) {
            r0[u] = fmaf(v0[u][0], A0.x, fmaf(v0[u][1], A0.y, fmaf(v0[u][2], A0.z, v0[u][3] * A0.w)));
            r1[u] = fmaf(v1[u][0], A1.x, fmaf(v1[u][1], A1.y, fmaf(v1[u][2], A1.z, v1[u][3] * A1.w)));
        }
#pragma unroll
        for (int u = 0; u < 8; u++) {
#pragma unroll
            for (int off = 8; off; off >>= 1) {
                r0[u] += __shfl_xor(r0[u], off);
                r1[u] += __shfl_xor(r1[u], off);
            }
        }
        if ((lane & 15) == 0) {
#pragma unroll
            for (int u = 0; u < 8; u++) {
                const int e = (i + u * DS_) >> 4;
                sc0[e] = r0[u];
                sc1[e] = r1[u];
            }
        }
    }
}

// K3: fused per-node softmax + aggregate + finalize. Wave per node.
// epair = {edge id, src} fused 8B gather; broadcast loop 4x-unrolled (deg is
// wave-uniform) for 4-deep MLP on the z-row loads.
__global__ __launch_bounds__(256) void node_sm_agg(
    const int* __restrict__ rowptr, const int2* __restrict__ epair,
    const float* __restrict__ score_t, const float* __restrict__ zs, const float* __restrict__ zd,
    const float* __restrict__ z, const float* __restrict__ base,
    float* __restrict__ out)
{
    const int lane = threadIdx.x & 63;
    const int n    = blockIdx.x * 4 + (threadIdx.x >> 6);
    if (n >= NN) return;

    const int s0  = rowptr[n], s1 = rowptr[n + 1];
    const int deg = s1 - s0;
    const float zdn = zd[n];

    float acc = 0.f;
    float ds;

    if (deg <= 64) {
        const int j = s0 + lane;
        int   sv = 0;
        float sc = -INFINITY;
        if (j < s1) {
            const int2 pr = epair[j];
            sv = pr.y;
            float v = score_t[pr.x] + zs[sv] + zdn;
            sc = (v >= 0.f) ? v : 0.01f * v;
        }
        float mx = sc;
#pragma unroll
        for (int off = 32; off; off >>= 1) mx = fmaxf(mx, __shfl_xor(mx, off));
        float ex = (j < s1) ? __expf(sc - mx) : 0.f;
        ds = ex;
#pragma unroll
        for (int off = 32; off; off >>= 1) ds += __shfl_xor(ds, off);

        int t = 0;
        for (; t + 4 <= deg; t += 4) {
            int   sa = __shfl(sv, t),     sb = __shfl(sv, t + 1);
            int   sc2 = __shfl(sv, t + 2), sd = __shfl(sv, t + 3);
            float ea = __shfl(ex, t),     eb = __shfl(ex, t + 1);
            float ec = __shfl(ex, t + 2), ed = __shfl(ex, t + 3);
            float za = z[(size_t)sa * 64 + lane];
            float zb = z[(size_t)sb * 64 + lane];
            float zc = z[(size_t)sc2 * 64 + lane];
            float zf = z[(size_t)sd * 64 + lane];
            acc = fmaf(ea, za, acc);
            acc = fmaf(eb, zb, acc);
            acc = fmaf(ec, zc, acc);
            acc = fmaf(ed, zf, acc);
        }
        for (; t < deg; t++) {
            int   s = __shfl(sv, t);
            float e = __shfl(ex, t);
            acc = fmaf(e, z[(size_t)s * 64 + lane], acc);
        }
    } else {
        // generic fallback (deg > 64): two passes, recompute scores.
        float mx = -INFINITY;
        for (int j = s0 + lane; j < s1; j += 64) {
            const int2 pr = epair[j];
            float v = score_t[pr.x] + zs[pr.y] + zdn;
            v = (v >= 0.f) ? v : 0.01f * v;
            mx = fmaxf(mx, v);
        }
#pragma unroll
        for (int off = 32; off; off >>= 1) mx = fmaxf(mx, __shfl_xor(mx, off));
        ds = 0.f;
        for (int c0 = s0; c0 < s1; c0 += 64) {
            const int j = c0 + lane;
            int   sv = 0;
            float ex = 0.f;
            if (j < s1) {
                const int2 pr = epair[j];
                sv = pr.y;
                float v = score_t[pr.x] + zs[sv] + zdn;
                v = (v >= 0.f) ? v : 0.01f * v;
                ex = __expf(v - mx);
            }
            ds += ex;
            const int cnt = min(64, s1 - c0);
            for (int t = 0; t < cnt; t++) {
                int   s = __shfl(sv, t);
                float e = __shfl(ex, t);
                acc = fmaf(e, z[(size_t)s * 64 + lane], acc);
            }
        }
#pragma unroll
        for (int off = 32; off; off >>= 1) ds += __shfl_xor(ds, off);
    }

    float r = 1.f / ((ds == 0.f) ? 1.f : ds);
    const size_t o = (size_t)n * 64 + lane;
    out[o] = acc * r + base[o];
}

// ---------------- launch ----------------

extern "C" void kernel_launch(void* const* d_in, const int* in_sizes, int n_in,
                              void* d_out, int out_size, void* d_ws, size_t ws_size,
                              hipStream_t stream)
{
    const float* attr  = (const float*)d_in[0];
    const float* pot0  = (const float*)d_in[1];
    const float* pot1  = (const float*)d_in[2];
    const float* et0   = (const float*)d_in[3];
    const float* et1   = (const float*)d_in[4];
    const float* Wpot  = (const float*)d_in[5];
    const float* bpot  = (const float*)d_in[6];
    const float* fcW0  = (const float*)d_in[7];
    const float* fcU0  = (const float*)d_in[8];
    const float* a0    = (const float*)d_in[9];
    const float* gate0 = (const float*)d_in[10];
    const float* fcW1  = (const float*)d_in[11];
    const float* fcU1  = (const float*)d_in[12];
    const float* a1    = (const float*)d_in[13];
    const float* gate1 = (const float*)d_in[14];
    const int*   src   = (const int*)d_in[15];
    const int*   dst   = (const int*)d_in[16];

    float* out = (float*)d_out;

    // workspace layout (epair 8B-aligned: offsets before it are even)
    float* ws      = (float*)d_ws;
    float* z       = ws;                    // NN*64
    float* base    = z + NN * 64;           // NN*64
    float* zs      = base + NN * 64;        // NN
    float* zd      = zs + NN;               // NN
    float* sc0     = zd + NN;               // EE (edge order)
    float* sc1     = sc0 + EE;              // EE (edge order)
    int*   rowptr  = (int*)(sc1 + EE);      // NN+1 (+1 pad)
    int*   deg     = rowptr + NN + 2;       // NN (becomes pos)
    int2*  epair   = (int2*)(deg + NN);     // EE  (8B aligned)

    const int eblk = (EE + 255) / 256;
    const int nblk = (NN + 3) / 4;
    const int tblk = (NN + BM - 1) / BM;

    // CSR build (shared by both layers)
    hipMemsetAsync(deg, 0, NN * sizeof(int), stream);
    k_hist<<<eblk, 256, 0, stream>>>(dst, deg);
    k_scan<<<1, 1024, 0, stream>>>(deg, rowptr);
    k_scatter<<<eblk, 256, 0, stream>>>(src, dst, deg, epair);

    // streaming edge dots for both layers (edge-order scores, nt loads)
    edge_dot2<<<DB, 256, 0, stream>>>(et0, et1, a0, a1, sc0, sc1);

    // ---------------- layer 0 ----------------
    node_transform<<<tblk, 256, 0, stream>>>(attr, pot0, Wpot, bpot, fcW0, fcU0,
                                             a0, gate0, z, zs, zd, base);
    node_sm_agg<<<nblk, 256, 0, stream>>>(rowptr, epair, sc0, zs, zd, z, base, out);

    // ---------------- layer 1 ---------------- (h = out from layer 0)
    node_transform<<<tblk, 256, 0, stream>>>(out, pot1, Wpot, bpot, fcW1, fcU1,
                                             a1, gate1, z, zs, zd, base);
    node_sm_agg<<<nblk, 256, 0, stream>>>(rowptr, epair, sc1, zs, zd, z, base, out);
}

// Round 10
// 391.239 us; speedup vs baseline: 1.9222x; 1.0699x over previous
//
#include <hip/hip_runtime.h>
#include <math.h>

#define NN 50000
#define EE 800000
#define BM 64
#define HB 3125                  // hist blocks (EE/256 exactly)
#define DB 1250                  // dot blocks
#define DS_ (DB * 256)           // dot stride; (EE*16) % (DS_*8) == 0
#define TB 782                   // transform blocks ((NN+63)/64)

typedef float f4 __attribute__((ext_vector_type(4)));

// ---------------- helpers ----------------

#define FMA4(acc, s, v) do { \
    (acc).x = fmaf((s), (v).x, (acc).x); \
    (acc).y = fmaf((s), (v).y, (acc).y); \
    (acc).z = fmaf((s), (v).z, (acc).z); \
    (acc).w = fmaf((s), (v).w, (acc).w); } while (0)

__device__ __forceinline__ float dot4(float4 u, float4 v) {
    return fmaf(u.x, v.x, fmaf(u.y, v.y, fmaf(u.z, v.z, u.w * v.w)));
}

// pack two finite floats to bf16 (RNE) in one uint: lo = feature even, hi = odd
__device__ __forceinline__ unsigned pk_bf16(float lo, float hi) {
    union { float f; unsigned u; } a, b;
    a.f = lo; b.f = hi;
    unsigned alo = (a.u + 0x7FFFu + ((a.u >> 16) & 1u)) >> 16;
    unsigned bhi = (b.u + 0x7FFFu + ((b.u >> 16) & 1u)) >> 16;
    return (bhi << 16) | alo;
}

__device__ __forceinline__ float upk_bf16(unsigned u, int odd) {
    union { unsigned u; float f; } r;
    r.u = odd ? (u & 0xFFFF0000u) : (u << 16);
    return r.f;
}

// ---------------- CSR scan / scatter ----------------

__global__ __launch_bounds__(1024) void k_scan(int* __restrict__ deg, int* __restrict__ rowptr) {
    __shared__ int part[1024];
    const int t  = threadIdx.x;
    const int CH = (NN + 1023) / 1024;
    const int b  = t * CH;
    const int e  = min(b + CH, NN);
    int sum = 0;
    for (int i = b; i < e; i++) sum += deg[i];
    part[t] = sum;
    __syncthreads();
    for (int off = 1; off < 1024; off <<= 1) {
        int v = (t >= off) ? part[t - off] : 0;
        __syncthreads();
        part[t] += v;
        __syncthreads();
    }
    int run = (t == 0) ? 0 : part[t - 1];
    for (int i = b; i < e; i++) {
        int d = deg[i];
        rowptr[i] = run;
        deg[i]    = run;   // pos
        run += d;
    }
    if (t == 0) rowptr[NN] = EE;
}

__global__ __launch_bounds__(256) void k_scatter(const int* __restrict__ src, const int* __restrict__ dst,
                                                 int* __restrict__ pos, int2* __restrict__ epair) {
    int e = blockIdx.x * 256 + threadIdx.x;
    if (e < EE) {
        int d = dst[e];
        int p = atomicAdd(&pos[d], 1);
        epair[p] = make_int2(e, src[e]);
    }
}

// ---------------- transform body (shared by mega + layer-1 kernel) ----------------

__device__ __forceinline__ void transform_body(
    int m0,
    const float* __restrict__ hin, const float* __restrict__ pot,
    const float* __restrict__ Wpot, const float* __restrict__ bpot,
    const float* __restrict__ fcW, const float* __restrict__ fcU,
    const float* __restrict__ a, const float* __restrict__ gate,
    unsigned* __restrict__ zb, float* __restrict__ zs, float* __restrict__ zd,
    float* __restrict__ base,
    float (*sAt)[64], float (*sB)[128], float (*sPot)[16], float (*sWp)[64])
{
    const int t     = threadIdx.x;
    const int valid = min(BM, NN - m0);

#pragma unroll
    for (int j = 0; j < 4; j++) {
        const int idx = t + j * 256;
        const int kw = idx >> 4, cq = idx & 15;
        *reinterpret_cast<float4*>(&sB[kw][cq * 4]) =
            *reinterpret_cast<const float4*>(fcW + kw * 64 + cq * 4);
        *reinterpret_cast<float4*>(&sB[kw][64 + cq * 4]) =
            *reinterpret_cast<const float4*>(fcU + kw * 64 + cq * 4);
    }
    {
        const int m = t >> 2, q = t & 3;
#pragma unroll
        for (int i = 0; i < 4; i++) {
            const int kg = i * 4 + q;
            float4 v4 = make_float4(0.f, 0.f, 0.f, 0.f);
            if (m < valid)
                v4 = *reinterpret_cast<const float4*>(hin + (size_t)(m0 + m) * 64 + kg * 4);
            sAt[kg * 4 + 0][m] = v4.x;
            sAt[kg * 4 + 1][m] = v4.y;
            sAt[kg * 4 + 2][m] = v4.z;
            sAt[kg * 4 + 3][m] = v4.w;
        }
        float4 p4 = make_float4(0.f, 0.f, 0.f, 0.f);
        if (m < valid)
            p4 = *reinterpret_cast<const float4*>(pot + (size_t)(m0 + m) * 16 + q * 4);
        *reinterpret_cast<float4*>(&sPot[m][q * 4]) = p4;
    }
    {
        const int kk = t >> 4, cq = t & 15;
        *reinterpret_cast<float4*>(&sWp[kk][cq * 4]) =
            *reinterpret_cast<const float4*>(Wpot + kk * 64 + cq * 4);
    }
    __syncthreads();

    const int c4 = (t & 15) * 4;
    const int r4 = (t >> 4) * 4;

    float4 az[4], au[4];
#pragma unroll
    for (int i = 0; i < 4; i++) {
        az[i] = make_float4(0.f, 0.f, 0.f, 0.f);
        au[i] = make_float4(0.f, 0.f, 0.f, 0.f);
    }

#pragma unroll 4
    for (int k = 0; k < 64; k++) {
        const float4 a4 = *reinterpret_cast<const float4*>(&sAt[k][r4]);
        const float4 bw = *reinterpret_cast<const float4*>(&sB[k][c4]);
        const float4 bu = *reinterpret_cast<const float4*>(&sB[k][64 + c4]);
        FMA4(az[0], a4.x, bw); FMA4(au[0], a4.x, bu);
        FMA4(az[1], a4.y, bw); FMA4(au[1], a4.y, bu);
        FMA4(az[2], a4.z, bw); FMA4(au[2], a4.z, bu);
        FMA4(az[3], a4.w, bw); FMA4(au[3], a4.w, bu);
    }

    {
        const float4 as4 = *reinterpret_cast<const float4*>(a + c4);
        const float4 ad4 = *reinterpret_cast<const float4*>(a + 64 + c4);
        float ps[4], pd[4];
#pragma unroll
        for (int i = 0; i < 4; i++) { ps[i] = dot4(az[i], as4); pd[i] = dot4(az[i], ad4); }
#pragma unroll
        for (int off = 1; off < 16; off <<= 1) {
#pragma unroll
            for (int i = 0; i < 4; i++) {
                ps[i] += __shfl_xor(ps[i], off);
                pd[i] += __shfl_xor(pd[i], off);
            }
        }
        if ((t & 15) == 0) {
#pragma unroll
            for (int i = 0; i < 4; i++) {
                if (r4 + i < valid) {
                    zs[m0 + r4 + i] = ps[i];
                    zd[m0 + r4 + i] = pd[i];
                }
            }
        }
    }

    {
        const float4 bp4 = *reinterpret_cast<const float4*>(bpot + c4);
        const float4 g4  = *reinterpret_cast<const float4*>(gate + c4);
        float4 vv[4] = {bp4, bp4, bp4, bp4};
#pragma unroll
        for (int kk = 0; kk < 16; kk++) {
            const float4 wp = *reinterpret_cast<const float4*>(&sWp[kk][c4]);
#pragma unroll
            for (int i = 0; i < 4; i++) {
                const float pv = sPot[r4 + i][kk];
                FMA4(vv[i], pv, wp);
            }
        }
#pragma unroll
        for (int i = 0; i < 4; i++) {
            if (r4 + i < valid) {
                const int n = m0 + r4 + i;
                // z as packed bf16: uint j holds features 2j (lo) / 2j+1 (hi)
                uint2 zp;
                zp.x = pk_bf16(az[i].x, az[i].y);
                zp.y = pk_bf16(az[i].z, az[i].w);
                *reinterpret_cast<uint2*>(zb + (size_t)n * 32 + c4 / 2) = zp;
                float4 b;
                b.x = g4.x * tanhf(vv[i].x) * au[i].x;
                b.y = g4.y * tanhf(vv[i].y) * au[i].y;
                b.z = g4.z * tanhf(vv[i].z) * au[i].z;
                b.w = g4.w * tanhf(vv[i].w) * au[i].w;
                *reinterpret_cast<float4*>(base + (size_t)n * 64 + c4) = b;
            }
        }
    }
}

// ---------------- mega front kernel: hist || edge dots || transform L0 ----------------

__global__ __launch_bounds__(256) void mega_front(
    const int* __restrict__ dst, int* __restrict__ deg,
    const float* __restrict__ et0, const float* __restrict__ et1,
    const float* __restrict__ a0, const float* __restrict__ a1,
    float* __restrict__ sc0, float* __restrict__ sc1,
    const float* __restrict__ attr, const float* __restrict__ pot0,
    const float* __restrict__ Wpot, const float* __restrict__ bpot,
    const float* __restrict__ fcW0, const float* __restrict__ fcU0,
    const float* __restrict__ gate0,
    unsigned* __restrict__ zb, float* __restrict__ zs, float* __restrict__ zd,
    float* __restrict__ base)
{
    __shared__ float sAt[64][64];
    __shared__ float sB[64][128];
    __shared__ float sPot[64][16];
    __shared__ float sWp[16][64];

    const int bid = blockIdx.x;

    if (bid < HB) {
        // ---- histogram of dst ----
        const int e = bid * 256 + threadIdx.x;   // HB*256 == EE exactly
        atomicAdd(&deg[dst[e]], 1);
    } else if (bid < HB + DB) {
        // ---- streaming edge dots (nt loads, lane-contiguous, 8-deep) ----
        const int tid  = (bid - HB) * 256 + threadIdx.x;
        const int lane = threadIdx.x & 63;
        const int p    = tid & 15;
        const float4 A0 = *reinterpret_cast<const float4*>(a0 + 128 + p * 4);
        const float4 A1 = *reinterpret_cast<const float4*>(a1 + 128 + p * 4);
        const f4* __restrict__ e0 = reinterpret_cast<const f4*>(et0);
        const f4* __restrict__ e1 = reinterpret_cast<const f4*>(et1);

        for (int i = tid; i < EE * 16; i += DS_ * 8) {
            f4 v0[8], v1[8];
#pragma unroll
            for (int u = 0; u < 8; u++) v0[u] = __builtin_nontemporal_load(e0 + i + u * DS_);
#pragma unroll
            for (int u = 0; u < 8; u++) v1[u] = __builtin_nontemporal_load(e1 + i + u * DS_);
            float r0[8], r1[8];
#pragma unroll
            for (int u = 0; u < 8; u++) {
                r0[u] = fmaf(v0[u][0], A0.x, fmaf(v0[u][1], A0.y, fmaf(v0[u][2], A0.z, v0[u][3] * A0.w)));
                r1[u] = fmaf(v1[u][0], A1.x, fmaf(v1[u][1], A1.y, fmaf(v1[u][2], A1.z, v1[u][3] * A1.w)));
            }
#pragma unroll
            for (int u = 0; u < 8; u++) {
#pragma unroll
                for (int off = 8; off; off >>= 1) {
                    r0[u] += __shfl_xor(r0[u], off);
                    r1[u] += __shfl_xor(r1[u], off);
                }
            }
            if ((lane & 15) == 0) {
#pragma unroll
                for (int u = 0; u < 8; u++) {
                    const int e = (i + u * DS_) >> 4;
                    sc0[e] = r0[u];
                    sc1[e] = r1[u];
                }
            }
        }
    } else {
        // ---- node transform, layer 0 ----
        transform_body((bid - HB - DB) * BM, attr, pot0, Wpot, bpot, fcW0, fcU0,
                       a0, gate0, zb, zs, zd, base, sAt, sB, sPot, sWp);
    }
}

// layer-1 transform (standalone)
__global__ __launch_bounds__(256) void node_transform(
    const float* __restrict__ hin, const float* __restrict__ pot,
    const float* __restrict__ Wpot, const float* __restrict__ bpot,
    const float* __restrict__ fcW, const float* __restrict__ fcU,
    const float* __restrict__ a, const float* __restrict__ gate,
    unsigned* __restrict__ zb, float* __restrict__ zs, float* __restrict__ zd,
    float* __restrict__ base)
{
    __shared__ float sAt[64][64];
    __shared__ float sB[64][128];
    __shared__ float sPot[64][16];
    __shared__ float sWp[16][64];
    transform_body(blockIdx.x * BM, hin, pot, Wpot, bpot, fcW, fcU, a, gate,
                   zb, zs, zd, base, sAt, sB, sPot, sWp);
}

// ---------------- fused softmax + aggregate (bf16 z gather) ----------------

__global__ __launch_bounds__(256) void node_sm_agg(
    const int* __restrict__ rowptr, const int2* __restrict__ epair,
    const float* __restrict__ score_t, const float* __restrict__ zs, const float* __restrict__ zd,
    const unsigned* __restrict__ zb, const float* __restrict__ base,
    float* __restrict__ out)
{
    const int lane = threadIdx.x & 63;
    const int n    = blockIdx.x * 4 + (threadIdx.x >> 6);
    if (n >= NN) return;

    const int s0  = rowptr[n], s1 = rowptr[n + 1];
    const int deg = s1 - s0;
    const float zdn = zd[n];
    const int half = lane >> 1;
    const int odd  = lane & 1;

    float acc = 0.f;
    float ds;

    if (deg <= 64) {
        const int j = s0 + lane;
        int   sv = 0;
        float sc = -INFINITY;
        if (j < s1) {
            const int2 pr = epair[j];
            sv = pr.y;
            float v = score_t[pr.x] + zs[sv] + zdn;
            sc = (v >= 0.f) ? v : 0.01f * v;
        }
        float mx = sc;
#pragma unroll
        for (int off = 32; off; off >>= 1) mx = fmaxf(mx, __shfl_xor(mx, off));
        float ex = (j < s1) ? __expf(sc - mx) : 0.f;
        ds = ex;
#pragma unroll
        for (int off = 32; off; off >>= 1) ds += __shfl_xor(ds, off);

        int t = 0;
        for (; t + 4 <= deg; t += 4) {
            int   sa = __shfl(sv, t),     sb = __shfl(sv, t + 1);
            int   sc2 = __shfl(sv, t + 2), sd = __shfl(sv, t + 3);
            float ea = __shfl(ex, t),     eb = __shfl(ex, t + 1);
            float ec = __shfl(ex, t + 2), ed = __shfl(ex, t + 3);
            unsigned ua = zb[(size_t)sa * 32 + half];
            unsigned ub = zb[(size_t)sb * 32 + half];
            unsigned uc = zb[(size_t)sc2 * 32 + half];
            unsigned ud = zb[(size_t)sd * 32 + half];
            acc = fmaf(ea, upk_bf16(ua, odd), acc);
            acc = fmaf(eb, upk_bf16(ub, odd), acc);
            acc = fmaf(ec, upk_bf16(uc, odd), acc);
            acc = fmaf(ed, upk_bf16(ud, odd), acc);
        }
        for (; t < deg; t++) {
            int   s = __shfl(sv, t);
            float e = __shfl(ex, t);
            acc = fmaf(e, upk_bf16(zb[(size_t)s * 32 + half], odd), acc);
        }
    } else {
        // generic fallback (deg > 64): two passes, recompute scores.
        float mx = -INFINITY;
        for (int j = s0 + lane; j < s1; j += 64) {
            const int2 pr = epair[j];
            float v = score_t[pr.x] + zs[pr.y] + zdn;
            v = (v >= 0.f) ? v : 0.01f * v;
            mx = fmaxf(mx, v);
        }
#pragma unroll
        for (int off = 32; off; off >>= 1) mx = fmaxf(mx, __shfl_xor(mx, off));
        ds = 0.f;
        for (int c0 = s0; c0 < s1; c0 += 64) {
            const int j = c0 + lane;
            int   sv = 0;
            float ex = 0.f;
            if (j < s1) {
                const int2 pr = epair[j];
                sv = pr.y;
                float v = score_t[pr.x] + zs[sv] + zdn;
                v = (v >= 0.f) ? v : 0.01f * v;
                ex = __expf(v - mx);
            }
            ds += ex;
            const int cnt = min(64, s1 - c0);
            for (int t = 0; t < cnt; t++) {
                int   s = __shfl(sv, t);
                float e = __shfl(ex, t);
                acc = fmaf(e, upk_bf16(zb[(size_t)s * 32 + half], odd), acc);
            }
        }
#pragma unroll
        for (int off = 32; off; off >>= 1) ds += __shfl_xor(ds, off);
    }

    float r = 1.f / ((ds == 0.f) ? 1.f : ds);
    const size_t o = (size_t)n * 64 + lane;
    out[o] = acc * r + base[o];
}

// ---------------- launch ----------------

extern "C" void kernel_launch(void* const* d_in, const int* in_sizes, int n_in,
                              void* d_out, int out_size, void* d_ws, size_t ws_size,
                              hipStream_t stream)
{
    const float* attr  = (const float*)d_in[0];
    const float* pot0  = (const float*)d_in[1];
    const float* pot1  = (const float*)d_in[2];
    const float* et0   = (const float*)d_in[3];
    const float* et1   = (const float*)d_in[4];
    const float* Wpot  = (const float*)d_in[5];
    const float* bpot  = (const float*)d_in[6];
    const float* fcW0  = (const float*)d_in[7];
    const float* fcU0  = (const float*)d_in[8];
    const float* a0    = (const float*)d_in[9];
    const float* gate0 = (const float*)d_in[10];
    const float* fcW1  = (const float*)d_in[11];
    const float* fcU1  = (const float*)d_in[12];
    const float* a1    = (const float*)d_in[13];
    const float* gate1 = (const float*)d_in[14];
    const int*   src   = (const int*)d_in[15];
    const int*   dst   = (const int*)d_in[16];

    float* out = (float*)d_out;

    // workspace layout (8B alignment maintained for epair)
    float*    ws     = (float*)d_ws;
    unsigned* zb     = (unsigned*)ws;            // NN*32 (bf16-packed z)
    float*    base   = (float*)(zb + NN * 32);   // NN*64
    float*    zs     = base + NN * 64;           // NN
    float*    zd     = zs + NN;                  // NN
    float*    sc0    = zd + NN;                  // EE
    float*    sc1    = sc0 + EE;                 // EE
    int*      rowptr = (int*)(sc1 + EE);         // NN+1 (+1 pad)
    int*      deg    = rowptr + NN + 2;          // NN (becomes pos)
    int2*     epair  = (int2*)(deg + NN);        // EE (8B aligned)

    const int eblk = (EE + 255) / 256;
    const int nblk = (NN + 3) / 4;

    // deg must be zero before mega_front's hist branch
    hipMemsetAsync(deg, 0, NN * sizeof(int), stream);

    // hist || edge dots || transform L0 in one dispatch
    mega_front<<<HB + DB + TB, 256, 0, stream>>>(
        dst, deg, et0, et1, a0, a1, sc0, sc1,
        attr, pot0, Wpot, bpot, fcW0, fcU0, gate0, zb, zs, zd, base);

    k_scan<<<1, 1024, 0, stream>>>(deg, rowptr);
    k_scatter<<<eblk, 256, 0, stream>>>(src, dst, deg, epair);

    // layer 0 aggregate
    node_sm_agg<<<nblk, 256, 0, stream>>>(rowptr, epair, sc0, zs, zd, zb, base, out);

    // layer 1
    node_transform<<<TB, 256, 0, stream>>>(out, pot1, Wpot, bpot, fcW1, fcU1,
                                           a1, gate1, zb, zs, zd, base);
    node_sm_agg<<<nblk, 256, 0, stream>>>(rowptr, epair, sc1, zs, zd, zb, base, out);
}

// Round 11
// 337.798 us; speedup vs baseline: 2.2263x; 1.1582x over previous
//
#include <hip/hip_runtime.h>
#include <math.h>

#define NN 50000
#define EE 800000
#define BM 64
#define HB 3125                  // hist blocks (EE/256 exactly)
#define DB 1250                  // dot blocks
#define DS_ (DB * 256)           // dot stride; (EE*16) % (DS_*8) == 0
#define TB 782                   // transform blocks ((NN+63)/64)

typedef float f4 __attribute__((ext_vector_type(4)));

// ---------------- helpers ----------------

#define FMA4(acc, s, v) do { \
    (acc).x = fmaf((s), (v).x, (acc).x); \
    (acc).y = fmaf((s), (v).y, (acc).y); \
    (acc).z = fmaf((s), (v).z, (acc).z); \
    (acc).w = fmaf((s), (v).w, (acc).w); } while (0)

__device__ __forceinline__ float dot4(float4 u, float4 v) {
    return fmaf(u.x, v.x, fmaf(u.y, v.y, fmaf(u.z, v.z, u.w * v.w)));
}

// pack two finite floats to bf16 (RNE) in one uint: lo = feature even, hi = odd
__device__ __forceinline__ unsigned pk_bf16(float lo, float hi) {
    union { float f; unsigned u; } a, b;
    a.f = lo; b.f = hi;
    unsigned alo = (a.u + 0x7FFFu + ((a.u >> 16) & 1u)) >> 16;
    unsigned bhi = (b.u + 0x7FFFu + ((b.u >> 16) & 1u)) >> 16;
    return (bhi << 16) | alo;
}

__device__ __forceinline__ float upk_bf16(unsigned u, int odd) {
    union { unsigned u; float f; } r;
    r.u = odd ? (u & 0xFFFF0000u) : (u << 16);
    return r.f;
}

// ---------------- fused histogram + edge dots (no LDS -> full occupancy) ----------------

__global__ __launch_bounds__(256) void hist_dot(
    const int* __restrict__ dst, int* __restrict__ deg, int* __restrict__ rank,
    const float* __restrict__ et0, const float* __restrict__ et1,
    const float* __restrict__ a0, const float* __restrict__ a1,
    float* __restrict__ sc0, float* __restrict__ sc1)
{
    const int bid = blockIdx.x;

    if (bid < HB) {
        // histogram + per-edge rank (atomicAdd return = rank within segment)
        const int e = bid * 256 + threadIdx.x;   // HB*256 == EE exactly
        rank[e] = atomicAdd(&deg[dst[e]], 1);
    } else {
        // streaming edge dots (nt loads, lane-contiguous, 8-deep unroll)
        const int tid  = (bid - HB) * 256 + threadIdx.x;
        const int lane = threadIdx.x & 63;
        const int p    = tid & 15;
        const float4 A0 = *reinterpret_cast<const float4*>(a0 + 128 + p * 4);
        const float4 A1 = *reinterpret_cast<const float4*>(a1 + 128 + p * 4);
        const f4* __restrict__ e0 = reinterpret_cast<const f4*>(et0);
        const f4* __restrict__ e1 = reinterpret_cast<const f4*>(et1);

        for (int i = tid; i < EE * 16; i += DS_ * 8) {
            f4 v0[8], v1[8];
#pragma unroll
            for (int u = 0; u < 8; u++) v0[u] = __builtin_nontemporal_load(e0 + i + u * DS_);
#pragma unroll
            for (int u = 0; u < 8; u++) v1[u] = __builtin_nontemporal_load(e1 + i + u * DS_);
            float r0[8], r1[8];
#pragma unroll
            for (int u = 0; u < 8; u++) {
                r0[u] = fmaf(v0[u][0], A0.x, fmaf(v0[u][1], A0.y, fmaf(v0[u][2], A0.z, v0[u][3] * A0.w)));
                r1[u] = fmaf(v1[u][0], A1.x, fmaf(v1[u][1], A1.y, fmaf(v1[u][2], A1.z, v1[u][3] * A1.w)));
            }
#pragma unroll
            for (int u = 0; u < 8; u++) {
#pragma unroll
                for (int off = 8; off; off >>= 1) {
                    r0[u] += __shfl_xor(r0[u], off);
                    r1[u] += __shfl_xor(r1[u], off);
                }
            }
            if ((lane & 15) == 0) {
#pragma unroll
                for (int u = 0; u < 8; u++) {
                    const int e = (i + u * DS_) >> 4;
                    sc0[e] = r0[u];
                    sc1[e] = r1[u];
                }
            }
        }
    }
}

// ---------------- CSR scan / atomic-free scatter ----------------

__global__ __launch_bounds__(1024) void k_scan(int* __restrict__ deg, int* __restrict__ rowptr) {
    __shared__ int part[1024];
    const int t  = threadIdx.x;
    const int CH = (NN + 1023) / 1024;
    const int b  = t * CH;
    const int e  = min(b + CH, NN);
    int sum = 0;
    for (int i = b; i < e; i++) sum += deg[i];
    part[t] = sum;
    __syncthreads();
    for (int off = 1; off < 1024; off <<= 1) {
        int v = (t >= off) ? part[t - off] : 0;
        __syncthreads();
        part[t] += v;
        __syncthreads();
    }
    int run = (t == 0) ? 0 : part[t - 1];
    for (int i = b; i < e; i++) {
        rowptr[i] = run;
        run += deg[i];
    }
    if (t == 0) rowptr[NN] = EE;
}

__global__ __launch_bounds__(256) void k_scatter(const int* __restrict__ src, const int* __restrict__ dst,
                                                 const int* __restrict__ rowptr, const int* __restrict__ rank,
                                                 int2* __restrict__ epair) {
    int e = blockIdx.x * 256 + threadIdx.x;
    if (e < EE) {
        int p = rowptr[dst[e]] + rank[e];
        epair[p] = make_int2(e, src[e]);
    }
}

// ---------------- node transform (LDS-tiled register-blocked GEMM) ----------------

__global__ __launch_bounds__(256) void node_transform(
    const float* __restrict__ hin, const float* __restrict__ pot,
    const float* __restrict__ Wpot, const float* __restrict__ bpot,
    const float* __restrict__ fcW, const float* __restrict__ fcU,
    const float* __restrict__ a, const float* __restrict__ gate,
    unsigned* __restrict__ zb, float* __restrict__ zs, float* __restrict__ zd,
    float* __restrict__ base)
{
    __shared__ float sAt[64][64];
    __shared__ float sB[64][128];
    __shared__ float sPot[64][16];
    __shared__ float sWp[16][64];

    const int t     = threadIdx.x;
    const int m0    = blockIdx.x * BM;
    const int valid = min(BM, NN - m0);

#pragma unroll
    for (int j = 0; j < 4; j++) {
        const int idx = t + j * 256;
        const int kw = idx >> 4, cq = idx & 15;
        *reinterpret_cast<float4*>(&sB[kw][cq * 4]) =
            *reinterpret_cast<const float4*>(fcW + kw * 64 + cq * 4);
        *reinterpret_cast<float4*>(&sB[kw][64 + cq * 4]) =
            *reinterpret_cast<const float4*>(fcU + kw * 64 + cq * 4);
    }
    {
        const int m = t >> 2, q = t & 3;
#pragma unroll
        for (int i = 0; i < 4; i++) {
            const int kg = i * 4 + q;
            float4 v4 = make_float4(0.f, 0.f, 0.f, 0.f);
            if (m < valid)
                v4 = *reinterpret_cast<const float4*>(hin + (size_t)(m0 + m) * 64 + kg * 4);
            sAt[kg * 4 + 0][m] = v4.x;
            sAt[kg * 4 + 1][m] = v4.y;
            sAt[kg * 4 + 2][m] = v4.z;
            sAt[kg * 4 + 3][m] = v4.w;
        }
        float4 p4 = make_float4(0.f, 0.f, 0.f, 0.f);
        if (m < valid)
            p4 = *reinterpret_cast<const float4*>(pot + (size_t)(m0 + m) * 16 + q * 4);
        *reinterpret_cast<float4*>(&sPot[m][q * 4]) = p4;
    }
    {
        const int kk = t >> 4, cq = t & 15;
        *reinterpret_cast<float4*>(&sWp[kk][cq * 4]) =
            *reinterpret_cast<const float4*>(Wpot + kk * 64 + cq * 4);
    }
    __syncthreads();

    const int c4 = (t & 15) * 4;
    const int r4 = (t >> 4) * 4;

    float4 az[4], au[4];
#pragma unroll
    for (int i = 0; i < 4; i++) {
        az[i] = make_float4(0.f, 0.f, 0.f, 0.f);
        au[i] = make_float4(0.f, 0.f, 0.f, 0.f);
    }

#pragma unroll 4
    for (int k = 0; k < 64; k++) {
        const float4 a4 = *reinterpret_cast<const float4*>(&sAt[k][r4]);
        const float4 bw = *reinterpret_cast<const float4*>(&sB[k][c4]);
        const float4 bu = *reinterpret_cast<const float4*>(&sB[k][64 + c4]);
        FMA4(az[0], a4.x, bw); FMA4(au[0], a4.x, bu);
        FMA4(az[1], a4.y, bw); FMA4(au[1], a4.y, bu);
        FMA4(az[2], a4.z, bw); FMA4(au[2], a4.z, bu);
        FMA4(az[3], a4.w, bw); FMA4(au[3], a4.w, bu);
    }

    {
        const float4 as4 = *reinterpret_cast<const float4*>(a + c4);
        const float4 ad4 = *reinterpret_cast<const float4*>(a + 64 + c4);
        float ps[4], pd[4];
#pragma unroll
        for (int i = 0; i < 4; i++) { ps[i] = dot4(az[i], as4); pd[i] = dot4(az[i], ad4); }
#pragma unroll
        for (int off = 1; off < 16; off <<= 1) {
#pragma unroll
            for (int i = 0; i < 4; i++) {
                ps[i] += __shfl_xor(ps[i], off);
                pd[i] += __shfl_xor(pd[i], off);
            }
        }
        if ((t & 15) == 0) {
#pragma unroll
            for (int i = 0; i < 4; i++) {
                if (r4 + i < valid) {
                    zs[m0 + r4 + i] = ps[i];
                    zd[m0 + r4 + i] = pd[i];
                }
            }
        }
    }

    {
        const float4 bp4 = *reinterpret_cast<const float4*>(bpot + c4);
        const float4 g4  = *reinterpret_cast<const float4*>(gate + c4);
        float4 vv[4] = {bp4, bp4, bp4, bp4};
#pragma unroll
        for (int kk = 0; kk < 16; kk++) {
            const float4 wp = *reinterpret_cast<const float4*>(&sWp[kk][c4]);
#pragma unroll
            for (int i = 0; i < 4; i++) {
                const float pv = sPot[r4 + i][kk];
                FMA4(vv[i], pv, wp);
            }
        }
#pragma unroll
        for (int i = 0; i < 4; i++) {
            if (r4 + i < valid) {
                const int n = m0 + r4 + i;
                uint2 zp;
                zp.x = pk_bf16(az[i].x, az[i].y);
                zp.y = pk_bf16(az[i].z, az[i].w);
                *reinterpret_cast<uint2*>(zb + (size_t)n * 32 + c4 / 2) = zp;
                float4 b;
                b.x = g4.x * tanhf(vv[i].x) * au[i].x;
                b.y = g4.y * tanhf(vv[i].y) * au[i].y;
                b.z = g4.z * tanhf(vv[i].z) * au[i].z;
                b.w = g4.w * tanhf(vv[i].w) * au[i].w;
                *reinterpret_cast<float4*>(base + (size_t)n * 64 + c4) = b;
            }
        }
    }
}

// ---------------- fused softmax + aggregate (bf16 z gather, 8-deep) ----------------

__global__ __launch_bounds__(256) void node_sm_agg(
    const int* __restrict__ rowptr, const int2* __restrict__ epair,
    const float* __restrict__ score_t, const float* __restrict__ zs, const float* __restrict__ zd,
    const unsigned* __restrict__ zb, const float* __restrict__ base,
    float* __restrict__ out)
{
    const int lane = threadIdx.x & 63;
    const int n    = blockIdx.x * 4 + (threadIdx.x >> 6);
    if (n >= NN) return;

    const int s0  = rowptr[n], s1 = rowptr[n + 1];
    const int deg = s1 - s0;
    const float zdn = zd[n];
    const int half = lane >> 1;
    const int odd  = lane & 1;

    float acc = 0.f;
    float ds;

    if (deg <= 64) {
        const int j = s0 + lane;
        int   sv = 0;
        float sc = -INFINITY;
        if (j < s1) {
            const int2 pr = epair[j];
            sv = pr.y;
            float v = score_t[pr.x] + zs[sv] + zdn;
            sc = (v >= 0.f) ? v : 0.01f * v;
        }
        float mx = sc;
#pragma unroll
        for (int off = 32; off; off >>= 1) mx = fmaxf(mx, __shfl_xor(mx, off));
        float ex = (j < s1) ? __expf(sc - mx) : 0.f;
        ds = ex;
#pragma unroll
        for (int off = 32; off; off >>= 1) ds += __shfl_xor(ds, off);

        int t = 0;
        for (; t + 8 <= deg; t += 8) {
            int   ss[8]; float ee[8]; unsigned uu[8];
#pragma unroll
            for (int u = 0; u < 8; u++) {
                ss[u] = __shfl(sv, t + u);
                ee[u] = __shfl(ex, t + u);
            }
#pragma unroll
            for (int u = 0; u < 8; u++) uu[u] = zb[(size_t)ss[u] * 32 + half];
#pragma unroll
            for (int u = 0; u < 8; u++) acc = fmaf(ee[u], upk_bf16(uu[u], odd), acc);
        }
        for (; t + 4 <= deg; t += 4) {
            int   ss[4]; float ee[4]; unsigned uu[4];
#pragma unroll
            for (int u = 0; u < 4; u++) {
                ss[u] = __shfl(sv, t + u);
                ee[u] = __shfl(ex, t + u);
            }
#pragma unroll
            for (int u = 0; u < 4; u++) uu[u] = zb[(size_t)ss[u] * 32 + half];
#pragma unroll
            for (int u = 0; u < 4; u++) acc = fmaf(ee[u], upk_bf16(uu[u], odd), acc);
        }
        for (; t < deg; t++) {
            int   s = __shfl(sv, t);
            float e = __shfl(ex, t);
            acc = fmaf(e, upk_bf16(zb[(size_t)s * 32 + half], odd), acc);
        }
    } else {
        // generic fallback (deg > 64): two passes, recompute scores.
        float mx = -INFINITY;
        for (int j = s0 + lane; j < s1; j += 64) {
            const int2 pr = epair[j];
            float v = score_t[pr.x] + zs[pr.y] + zdn;
            v = (v >= 0.f) ? v : 0.01f * v;
            mx = fmaxf(mx, v);
        }
#pragma unroll
        for (int off = 32; off; off >>= 1) mx = fmaxf(mx, __shfl_xor(mx, off));
        ds = 0.f;
        for (int c0 = s0; c0 < s1; c0 += 64) {
            const int j = c0 + lane;
            int   sv = 0;
            float ex = 0.f;
            if (j < s1) {
                const int2 pr = epair[j];
                sv = pr.y;
                float v = score_t[pr.x] + zs[sv] + zdn;
                v = (v >= 0.f) ? v : 0.01f * v;
                ex = __expf(v - mx);
            }
            ds += ex;
            const int cnt = min(64, s1 - c0);
            for (int t = 0; t < cnt; t++) {
                int   s = __shfl(sv, t);
                float e = __shfl(ex, t);
                acc = fmaf(e, upk_bf16(zb[(size_t)s * 32 + half], odd), acc);
            }
        }
#pragma unroll
        for (int off = 32; off; off >>= 1) ds += __shfl_xor(ds, off);
    }

    float r = 1.f / ((ds == 0.f) ? 1.f : ds);
    const size_t o = (size_t)n * 64 + lane;
    out[o] = acc * r + base[o];
}

// ---------------- launch ----------------

extern "C" void kernel_launch(void* const* d_in, const int* in_sizes, int n_in,
                              void* d_out, int out_size, void* d_ws, size_t ws_size,
                              hipStream_t stream)
{
    const float* attr  = (const float*)d_in[0];
    const float* pot0  = (const float*)d_in[1];
    const float* pot1  = (const float*)d_in[2];
    const float* et0   = (const float*)d_in[3];
    const float* et1   = (const float*)d_in[4];
    const float* Wpot  = (const float*)d_in[5];
    const float* bpot  = (const float*)d_in[6];
    const float* fcW0  = (const float*)d_in[7];
    const float* fcU0  = (const float*)d_in[8];
    const float* a0    = (const float*)d_in[9];
    const float* gate0 = (const float*)d_in[10];
    const float* fcW1  = (const float*)d_in[11];
    const float* fcU1  = (const float*)d_in[12];
    const float* a1    = (const float*)d_in[13];
    const float* gate1 = (const float*)d_in[14];
    const int*   src   = (const int*)d_in[15];
    const int*   dst   = (const int*)d_in[16];

    float* out = (float*)d_out;

    // workspace layout (epair offset even in 4B units -> 8B aligned)
    float*    ws     = (float*)d_ws;
    unsigned* zb     = (unsigned*)ws;            // NN*32 (bf16-packed z)
    float*    base   = (float*)(zb + NN * 32);   // NN*64
    float*    zs     = base + NN * 64;           // NN
    float*    zd     = zs + NN;                  // NN
    float*    sc0    = zd + NN;                  // EE
    float*    sc1    = sc0 + EE;                 // EE
    int*      rowptr = (int*)(sc1 + EE);         // NN+1 (+1 pad)
    int*      deg    = rowptr + NN + 2;          // NN
    int*      rank   = deg + NN;                 // EE
    int2*     epair  = (int2*)(rank + EE);       // EE (8B aligned)

    const int eblk = (EE + 255) / 256;
    const int nblk = (NN + 3) / 4;

    // deg must be zero before hist
    hipMemsetAsync(deg, 0, NN * sizeof(int), stream);

    // hist (+rank) || edge dots, zero LDS -> full occupancy
    hist_dot<<<HB + DB, 256, 0, stream>>>(dst, deg, rank, et0, et1, a0, a1, sc0, sc1);

    // transform L0 (independent of CSR)
    node_transform<<<TB, 256, 0, stream>>>(attr, pot0, Wpot, bpot, fcW0, fcU0,
                                           a0, gate0, zb, zs, zd, base);

    k_scan<<<1, 1024, 0, stream>>>(deg, rowptr);
    k_scatter<<<eblk, 256, 0, stream>>>(src, dst, rowptr, rank, epair);

    // layer 0 aggregate
    node_sm_agg<<<nblk, 256, 0, stream>>>(rowptr, epair, sc0, zs, zd, zb, base, out);

    // layer 1
    node_transform<<<TB, 256, 0, stream>>>(out, pot1, Wpot, bpot, fcW1, fcU1,
                                           a1, gate1, zb, zs, zd, base);
    node_sm_agg<<<nblk, 256, 0, stream>>>(rowptr, epair, sc1, zs, zd, zb, base, out);
}

// Round 12
// 330.674 us; speedup vs baseline: 2.2743x; 1.0215x over previous
//
#include <hip/hip_runtime.h>
#include <math.h>

#define NN 50000
#define EE 800000
#define BM 64
#define HB 3125                  // hist blocks (EE/256 exactly)
#define DB 2500                  // dot blocks
#define DS2 (DB * 256)           // 640000; (EE*16) % (DS2*4) == 0 -> 5 iters
#define TB 782                   // transform blocks ((NN+63)/64)

typedef float f4 __attribute__((ext_vector_type(4)));

// ---------------- helpers ----------------

#define FMA4(acc, s, v) do { \
    (acc).x = fmaf((s), (v).x, (acc).x); \
    (acc).y = fmaf((s), (v).y, (acc).y); \
    (acc).z = fmaf((s), (v).z, (acc).z); \
    (acc).w = fmaf((s), (v).w, (acc).w); } while (0)

__device__ __forceinline__ float dot4(float4 u, float4 v) {
    return fmaf(u.x, v.x, fmaf(u.y, v.y, fmaf(u.z, v.z, u.w * v.w)));
}

// pack two finite floats to bf16 (RNE) in one uint: lo = feature even, hi = odd
__device__ __forceinline__ unsigned pk_bf16(float lo, float hi) {
    union { float f; unsigned u; } a, b;
    a.f = lo; b.f = hi;
    unsigned alo = (a.u + 0x7FFFu + ((a.u >> 16) & 1u)) >> 16;
    unsigned bhi = (b.u + 0x7FFFu + ((b.u >> 16) & 1u)) >> 16;
    return (bhi << 16) | alo;
}

__device__ __forceinline__ float upk_bf16(unsigned u, int odd) {
    union { unsigned u; float f; } r;
    r.u = odd ? (u & 0xFFFF0000u) : (u << 16);
    return r.f;
}

// ---------------- fused histogram + edge dots (no LDS -> full occupancy) ----------------

__global__ __launch_bounds__(256) void hist_dot(
    const int* __restrict__ dst, int* __restrict__ deg, int* __restrict__ rank,
    const float* __restrict__ et0, const float* __restrict__ et1,
    const float* __restrict__ a0, const float* __restrict__ a1,
    float* __restrict__ sc0, float* __restrict__ sc1)
{
    const int bid = blockIdx.x;

    if (bid < HB) {
        // histogram + per-edge rank (atomicAdd return = rank within segment)
        const int e = bid * 256 + threadIdx.x;   // HB*256 == EE exactly
        rank[e] = atomicAdd(&deg[dst[e]], 1);
    } else {
        // streaming edge dots (nt loads, lane-contiguous, 4-deep unroll)
        const int tid  = (bid - HB) * 256 + threadIdx.x;
        const int lane = threadIdx.x & 63;
        const int p    = tid & 15;
        const float4 A0 = *reinterpret_cast<const float4*>(a0 + 128 + p * 4);
        const float4 A1 = *reinterpret_cast<const float4*>(a1 + 128 + p * 4);
        const f4* __restrict__ e0 = reinterpret_cast<const f4*>(et0);
        const f4* __restrict__ e1 = reinterpret_cast<const f4*>(et1);

        for (int i = tid; i < EE * 16; i += DS2 * 4) {
            f4 v0[4], v1[4];
#pragma unroll
            for (int u = 0; u < 4; u++) v0[u] = __builtin_nontemporal_load(e0 + i + u * DS2);
#pragma unroll
            for (int u = 0; u < 4; u++) v1[u] = __builtin_nontemporal_load(e1 + i + u * DS2);
            float r0[4], r1[4];
#pragma unroll
            for (int u = 0; u < 4; u++) {
                r0[u] = fmaf(v0[u][0], A0.x, fmaf(v0[u][1], A0.y, fmaf(v0[u][2], A0.z, v0[u][3] * A0.w)));
                r1[u] = fmaf(v1[u][0], A1.x, fmaf(v1[u][1], A1.y, fmaf(v1[u][2], A1.z, v1[u][3] * A1.w)));
            }
#pragma unroll
            for (int u = 0; u < 4; u++) {
#pragma unroll
                for (int off = 8; off; off >>= 1) {
                    r0[u] += __shfl_xor(r0[u], off);
                    r1[u] += __shfl_xor(r1[u], off);
                }
            }
            if ((lane & 15) == 0) {
#pragma unroll
                for (int u = 0; u < 4; u++) {
                    const int e = (i + u * DS2) >> 4;
                    sc0[e] = r0[u];
                    sc1[e] = r1[u];
                }
            }
        }
    }
}

// ---------------- atomic-free scatter: epX[p] = {src, score bits} ----------------

__global__ __launch_bounds__(256) void k_scatter(
    const int* __restrict__ src, const int* __restrict__ dst,
    const int* __restrict__ rowptr, const int* __restrict__ rank,
    const float* __restrict__ sc0, const float* __restrict__ sc1,
    int2* __restrict__ epA, int2* __restrict__ epB)
{
    int e = blockIdx.x * 256 + threadIdx.x;
    if (e < EE) {
        const int p = rowptr[dst[e]] + rank[e];
        const int s = src[e];
        epA[p] = make_int2(s, __float_as_int(sc0[e]));
        epB[p] = make_int2(s, __float_as_int(sc1[e]));
    }
}

// ---------------- node transform (LDS-tiled GEMM) + optional fused scan block ----------------

__global__ __launch_bounds__(256) void node_transform(
    const float* __restrict__ hin, const float* __restrict__ pot,
    const float* __restrict__ Wpot, const float* __restrict__ bpot,
    const float* __restrict__ fcW, const float* __restrict__ fcU,
    const float* __restrict__ a, const float* __restrict__ gate,
    unsigned* __restrict__ zb, float* __restrict__ zs, float* __restrict__ zd,
    float* __restrict__ base,
    const int* __restrict__ deg, int* __restrict__ rowptr, int do_scan)
{
    __shared__ float sAt[64][64];
    __shared__ float sB[64][128];
    __shared__ float sPot[64][16];
    __shared__ float sWp[16][64];

    const int t = threadIdx.x;

    if (do_scan && blockIdx.x == TB) {
        // 256-thread exclusive scan of deg -> rowptr (rides in this dispatch)
        int* part = reinterpret_cast<int*>(&sAt[0][0]);
        const int CH = (NN + 255) / 256;
        const int b  = t * CH;
        const int e  = min(b + CH, NN);
        int sum = 0;
        for (int i = b; i < e; i++) sum += deg[i];
        part[t] = sum;
        __syncthreads();
        for (int off = 1; off < 256; off <<= 1) {
            int v = (t >= off) ? part[t - off] : 0;
            __syncthreads();
            part[t] += v;
            __syncthreads();
        }
        int run = (t == 0) ? 0 : part[t - 1];
        for (int i = b; i < e; i++) {
            rowptr[i] = run;
            run += deg[i];
        }
        if (t == 0) rowptr[NN] = EE;
        return;
    }

    const int m0    = blockIdx.x * BM;
    const int valid = min(BM, NN - m0);

#pragma unroll
    for (int j = 0; j < 4; j++) {
        const int idx = t + j * 256;
        const int kw = idx >> 4, cq = idx & 15;
        *reinterpret_cast<float4*>(&sB[kw][cq * 4]) =
            *reinterpret_cast<const float4*>(fcW + kw * 64 + cq * 4);
        *reinterpret_cast<float4*>(&sB[kw][64 + cq * 4]) =
            *reinterpret_cast<const float4*>(fcU + kw * 64 + cq * 4);
    }
    {
        const int m = t >> 2, q = t & 3;
#pragma unroll
        for (int i = 0; i < 4; i++) {
            const int kg = i * 4 + q;
            float4 v4 = make_float4(0.f, 0.f, 0.f, 0.f);
            if (m < valid)
                v4 = *reinterpret_cast<const float4*>(hin + (size_t)(m0 + m) * 64 + kg * 4);
            sAt[kg * 4 + 0][m] = v4.x;
            sAt[kg * 4 + 1][m] = v4.y;
            sAt[kg * 4 + 2][m] = v4.z;
            sAt[kg * 4 + 3][m] = v4.w;
        }
        float4 p4 = make_float4(0.f, 0.f, 0.f, 0.f);
        if (m < valid)
            p4 = *reinterpret_cast<const float4*>(pot + (size_t)(m0 + m) * 16 + q * 4);
        *reinterpret_cast<float4*>(&sPot[m][q * 4]) = p4;
    }
    {
        const int kk = t >> 4, cq = t & 15;
        *reinterpret_cast<float4*>(&sWp[kk][cq * 4]) =
            *reinterpret_cast<const float4*>(Wpot + kk * 64 + cq * 4);
    }
    __syncthreads();

    const int c4 = (t & 15) * 4;
    const int r4 = (t >> 4) * 4;

    float4 az[4], au[4];
#pragma unroll
    for (int i = 0; i < 4; i++) {
        az[i] = make_float4(0.f, 0.f, 0.f, 0.f);
        au[i] = make_float4(0.f, 0.f, 0.f, 0.f);
    }

#pragma unroll 4
    for (int k = 0; k < 64; k++) {
        const float4 a4 = *reinterpret_cast<const float4*>(&sAt[k][r4]);
        const float4 bw = *reinterpret_cast<const float4*>(&sB[k][c4]);
        const float4 bu = *reinterpret_cast<const float4*>(&sB[k][64 + c4]);
        FMA4(az[0], a4.x, bw); FMA4(au[0], a4.x, bu);
        FMA4(az[1], a4.y, bw); FMA4(au[1], a4.y, bu);
        FMA4(az[2], a4.z, bw); FMA4(au[2], a4.z, bu);
        FMA4(az[3], a4.w, bw); FMA4(au[3], a4.w, bu);
    }

    {
        const float4 as4 = *reinterpret_cast<const float4*>(a + c4);
        const float4 ad4 = *reinterpret_cast<const float4*>(a + 64 + c4);
        float ps[4], pd[4];
#pragma unroll
        for (int i = 0; i < 4; i++) { ps[i] = dot4(az[i], as4); pd[i] = dot4(az[i], ad4); }
#pragma unroll
        for (int off = 1; off < 16; off <<= 1) {
#pragma unroll
            for (int i = 0; i < 4; i++) {
                ps[i] += __shfl_xor(ps[i], off);
                pd[i] += __shfl_xor(pd[i], off);
            }
        }
        if ((t & 15) == 0) {
#pragma unroll
            for (int i = 0; i < 4; i++) {
                if (r4 + i < valid) {
                    zs[m0 + r4 + i] = ps[i];
                    zd[m0 + r4 + i] = pd[i];
                }
            }
        }
    }

    {
        const float4 bp4 = *reinterpret_cast<const float4*>(bpot + c4);
        const float4 g4  = *reinterpret_cast<const float4*>(gate + c4);
        float4 vv[4] = {bp4, bp4, bp4, bp4};
#pragma unroll
        for (int kk = 0; kk < 16; kk++) {
            const float4 wp = *reinterpret_cast<const float4*>(&sWp[kk][c4]);
#pragma unroll
            for (int i = 0; i < 4; i++) {
                const float pv = sPot[r4 + i][kk];
                FMA4(vv[i], pv, wp);
            }
        }
#pragma unroll
        for (int i = 0; i < 4; i++) {
            if (r4 + i < valid) {
                const int n = m0 + r4 + i;
                uint2 zp;
                zp.x = pk_bf16(az[i].x, az[i].y);
                zp.y = pk_bf16(az[i].z, az[i].w);
                *reinterpret_cast<uint2*>(zb + (size_t)n * 32 + c4 / 2) = zp;
                float4 b;
                b.x = g4.x * tanhf(vv[i].x) * au[i].x;
                b.y = g4.y * tanhf(vv[i].y) * au[i].y;
                b.z = g4.z * tanhf(vv[i].z) * au[i].z;
                b.w = g4.w * tanhf(vv[i].w) * au[i].w;
                *reinterpret_cast<float4*>(base + (size_t)n * 64 + c4) = b;
            }
        }
    }
}

// ---------------- fused softmax + aggregate (score-embedded CSR, bf16 z) ----------------

__global__ __launch_bounds__(256) void node_sm_agg(
    const int* __restrict__ rowptr, const int2* __restrict__ ep,
    const float* __restrict__ zs, const float* __restrict__ zd,
    const unsigned* __restrict__ zb, const float* __restrict__ base,
    float* __restrict__ out)
{
    const int lane = threadIdx.x & 63;
    const int n    = blockIdx.x * 4 + (threadIdx.x >> 6);
    if (n >= NN) return;

    const int s0  = rowptr[n], s1 = rowptr[n + 1];
    const int deg = s1 - s0;
    const float zdn = zd[n];
    const int half = lane >> 1;
    const int odd  = lane & 1;

    float acc = 0.f;
    float ds;

    if (deg <= 64) {
        const int j = s0 + lane;
        int   sv = 0;
        float sc = -INFINITY;
        if (j < s1) {
            const int2 pr = ep[j];
            sv = pr.x;
            float v = __int_as_float(pr.y) + zs[sv] + zdn;
            sc = (v >= 0.f) ? v : 0.01f * v;
        }
        float mx = sc;
#pragma unroll
        for (int off = 32; off; off >>= 1) mx = fmaxf(mx, __shfl_xor(mx, off));
        float ex = (j < s1) ? __expf(sc - mx) : 0.f;
        ds = ex;
#pragma unroll
        for (int off = 32; off; off >>= 1) ds += __shfl_xor(ds, off);

        int t = 0;
        for (; t + 8 <= deg; t += 8) {
            int   ss[8]; float ee[8]; unsigned uu[8];
#pragma unroll
            for (int u = 0; u < 8; u++) {
                ss[u] = __shfl(sv, t + u);
                ee[u] = __shfl(ex, t + u);
            }
#pragma unroll
            for (int u = 0; u < 8; u++) uu[u] = zb[(size_t)ss[u] * 32 + half];
#pragma unroll
            for (int u = 0; u < 8; u++) acc = fmaf(ee[u], upk_bf16(uu[u], odd), acc);
        }
        for (; t + 4 <= deg; t += 4) {
            int   ss[4]; float ee[4]; unsigned uu[4];
#pragma unroll
            for (int u = 0; u < 4; u++) {
                ss[u] = __shfl(sv, t + u);
                ee[u] = __shfl(ex, t + u);
            }
#pragma unroll
            for (int u = 0; u < 4; u++) uu[u] = zb[(size_t)ss[u] * 32 + half];
#pragma unroll
            for (int u = 0; u < 4; u++) acc = fmaf(ee[u], upk_bf16(uu[u], odd), acc);
        }
        for (; t < deg; t++) {
            int   s = __shfl(sv, t);
            float e = __shfl(ex, t);
            acc = fmaf(e, upk_bf16(zb[(size_t)s * 32 + half], odd), acc);
        }
    } else {
        // generic fallback (deg > 64): two passes.
        float mx = -INFINITY;
        for (int j = s0 + lane; j < s1; j += 64) {
            const int2 pr = ep[j];
            float v = __int_as_float(pr.y) + zs[pr.x] + zdn;
            v = (v >= 0.f) ? v : 0.01f * v;
            mx = fmaxf(mx, v);
        }
#pragma unroll
        for (int off = 32; off; off >>= 1) mx = fmaxf(mx, __shfl_xor(mx, off));
        ds = 0.f;
        for (int c0 = s0; c0 < s1; c0 += 64) {
            const int j = c0 + lane;
            int   sv = 0;
            float ex = 0.f;
            if (j < s1) {
                const int2 pr = ep[j];
                sv = pr.x;
                float v = __int_as_float(pr.y) + zs[sv] + zdn;
                v = (v >= 0.f) ? v : 0.01f * v;
                ex = __expf(v - mx);
            }
            ds += ex;
            const int cnt = min(64, s1 - c0);
            for (int t = 0; t < cnt; t++) {
                int   s = __shfl(sv, t);
                float e = __shfl(ex, t);
                acc = fmaf(e, upk_bf16(zb[(size_t)s * 32 + half], odd), acc);
            }
        }
#pragma unroll
        for (int off = 32; off; off >>= 1) ds += __shfl_xor(ds, off);
    }

    float r = 1.f / ((ds == 0.f) ? 1.f : ds);
    const size_t o = (size_t)n * 64 + lane;
    out[o] = acc * r + base[o];
}

// ---------------- launch ----------------

extern "C" void kernel_launch(void* const* d_in, const int* in_sizes, int n_in,
                              void* d_out, int out_size, void* d_ws, size_t ws_size,
                              hipStream_t stream)
{
    const float* attr  = (const float*)d_in[0];
    const float* pot0  = (const float*)d_in[1];
    const float* pot1  = (const float*)d_in[2];
    const float* et0   = (const float*)d_in[3];
    const float* et1   = (const float*)d_in[4];
    const float* Wpot  = (const float*)d_in[5];
    const float* bpot  = (const float*)d_in[6];
    const float* fcW0  = (const float*)d_in[7];
    const float* fcU0  = (const float*)d_in[8];
    const float* a0    = (const float*)d_in[9];
    const float* gate0 = (const float*)d_in[10];
    const float* fcW1  = (const float*)d_in[11];
    const float* fcU1  = (const float*)d_in[12];
    const float* a1    = (const float*)d_in[13];
    const float* gate1 = (const float*)d_in[14];
    const int*   src   = (const int*)d_in[15];
    const int*   dst   = (const int*)d_in[16];

    float* out = (float*)d_out;

    // workspace layout: 8B-aligned int2 arrays first
    int2*     epA    = (int2*)d_ws;              // EE
    int2*     epB    = epA + EE;                 // EE
    unsigned* zb     = (unsigned*)(epB + EE);    // NN*32 (bf16-packed z)
    float*    base   = (float*)(zb + NN * 32);   // NN*64
    float*    zs     = base + NN * 64;           // NN
    float*    zd     = zs + NN;                  // NN
    float*    sc0    = zd + NN;                  // EE
    float*    sc1    = sc0 + EE;                 // EE
    int*      rowptr = (int*)(sc1 + EE);         // NN+1
    int*      deg    = rowptr + NN + 1;          // NN
    int*      rank   = deg + NN;                 // EE

    const int eblk = (EE + 255) / 256;
    const int nblk = (NN + 3) / 4;

    // deg must be zero before hist
    hipMemsetAsync(deg, 0, NN * sizeof(int), stream);

    // hist (+rank) || edge dots, zero LDS -> high occupancy
    hist_dot<<<HB + DB, 256, 0, stream>>>(dst, deg, rank, et0, et1, a0, a1, sc0, sc1);

    // transform L0 + fused scan block (scan needs deg, complete after hist_dot)
    node_transform<<<TB + 1, 256, 0, stream>>>(attr, pot0, Wpot, bpot, fcW0, fcU0,
                                               a0, gate0, zb, zs, zd, base,
                                               deg, rowptr, 1);

    // atomic-free scatter with embedded scores
    k_scatter<<<eblk, 256, 0, stream>>>(src, dst, rowptr, rank, sc0, sc1, epA, epB);

    // layer 0 aggregate
    node_sm_agg<<<nblk, 256, 0, stream>>>(rowptr, epA, zs, zd, zb, base, out);

    // layer 1
    node_transform<<<TB, 256, 0, stream>>>(out, pot1, Wpot, bpot, fcW1, fcU1,
                                           a1, gate1, zb, zs, zd, base,
                                           deg, rowptr, 0);
    node_sm_agg<<<nblk, 256, 0, stream>>>(rowptr, epB, zs, zd, zb, base, out);
}